// Round 1
// baseline (1175.298 us; speedup 1.0000x reference)
//
#include <hip/hip_runtime.h>

typedef __bf16 bf16;
typedef __bf16 bf16x8 __attribute__((ext_vector_type(8)));
typedef float f32x4 __attribute__((ext_vector_type(4)));

#define NTOK 16384
#define DMODEL 1024
#define HFFN 4096
#define NEXP 8
#define CAP 2048

__device__ __forceinline__ void gload16(const void* g, void* l) {
  __builtin_amdgcn_global_load_lds((const __attribute__((address_space(1))) void*)g,
                                   (__attribute__((address_space(3))) void*)l, 16, 0, 0);
}

__device__ __forceinline__ float gelu_f(float v) {
  // tanh-approx gelu (jax.nn.gelu default), tanh via exp
  float u = 0.7978845608028654f * (v + 0.044715f * v * v * v);
  float ex = __expf(2.0f * u);
  float th = 1.0f - 2.0f / (ex + 1.0f);
  return 0.5f * v * (1.0f + th);
}

// ---------------- x: f32 -> bf16 ----------------
__global__ __launch_bounds__(256) void cvt_x_kernel(const float* __restrict__ x,
                                                    bf16* __restrict__ xb) {
  int i = blockIdx.x * blockDim.x + threadIdx.x;  // 8 elems per thread
  const float4* a = (const float4*)x + (size_t)i * 2;
  float4 v0 = a[0], v1 = a[1];
  bf16x8 o;
  o[0]=(bf16)v0.x; o[1]=(bf16)v0.y; o[2]=(bf16)v0.z; o[3]=(bf16)v0.w;
  o[4]=(bf16)v1.x; o[5]=(bf16)v1.y; o[6]=(bf16)v1.z; o[7]=(bf16)v1.w;
  *(bf16x8*)(xb + (size_t)i * 8) = o;
}

// ---------------- router: probs[e][t] (f32, full precision) ----------------
__global__ __launch_bounds__(64) void router_kernel(const float* __restrict__ x,
                                                    const float* __restrict__ gw,
                                                    float* __restrict__ probs) {
  int t = blockIdx.x;
  int l = threadIdx.x;
  int e = l & 7, chunk = l >> 3;           // 8 experts x 8 d-chunks of 128
  const float* xr = x + (size_t)t * DMODEL + chunk * 128;
  const float* gwr = gw + (size_t)(chunk * 128) * NEXP + e;
  float a0 = 0.f, a1 = 0.f;
  #pragma unroll
  for (int d = 0; d < 128; d += 8) {
    float4 xv = *(const float4*)(xr + d);
    float4 xw = *(const float4*)(xr + d + 4);
    a0 += xv.x * gwr[(d+0)*8] + xv.y * gwr[(d+1)*8] + xv.z * gwr[(d+2)*8] + xv.w * gwr[(d+3)*8];
    a1 += xw.x * gwr[(d+4)*8] + xw.y * gwr[(d+5)*8] + xw.z * gwr[(d+6)*8] + xw.w * gwr[(d+7)*8];
  }
  float acc = a0 + a1;
  acc += __shfl_xor(acc, 8);
  acc += __shfl_xor(acc, 16);
  acc += __shfl_xor(acc, 32);              // every lane: full logit for expert e
  float m = acc;
  m = fmaxf(m, __shfl_xor(m, 1));
  m = fmaxf(m, __shfl_xor(m, 2));
  m = fmaxf(m, __shfl_xor(m, 4));
  float ex = expf(acc - m);
  float s = ex;
  s += __shfl_xor(s, 1); s += __shfl_xor(s, 2); s += __shfl_xor(s, 4);
  if (l < 8) probs[(size_t)e * NTOK + t] = ex / s;
}

// ---------------- per-expert top-2048 radix select ----------------
// Exact k-th-largest threshold via 4x8-bit radix; > thr all taken (any order ok:
// set semantics), == thr taken in ascending token index (lax.top_k stability).
__global__ __launch_bounds__(256) void topk_kernel(const float* __restrict__ probs,
                                                   int* __restrict__ oidx,
                                                   float* __restrict__ oscr) {
  const int e = blockIdx.x;
  const float* p = probs + (size_t)e * NTOK;
  const int t = threadIdx.x;  // 256 threads, 64 contiguous tokens each
  __shared__ unsigned hist[256];
  __shared__ unsigned sg[256], sq[256];
  __shared__ unsigned bcast[4];
  unsigned pref = 0, krem = CAP;
  for (int pass = 0; pass < 4; ++pass) {
    const int sh = 24 - pass * 8;
    hist[t] = 0;
    __syncthreads();
    for (int j = 0; j < 64; ++j) {
      unsigned u = __float_as_uint(p[t * 64 + j]);
      bool ok = (pass == 0) || ((u >> (sh + 8)) == pref);
      if (ok) atomicAdd(&hist[(u >> sh) & 255u], 1u);
    }
    __syncthreads();
    if (t == 0) {
      unsigned cum = 0; int b = 255;
      for (; b > 0; --b) {
        unsigned c = hist[b];
        if (cum + c >= krem) break;
        cum += c;
      }
      bcast[0] = (pref << 8) | (unsigned)b;
      bcast[1] = krem - cum;
    }
    __syncthreads();
    pref = bcast[0];
    krem = bcast[1];
  }
  const unsigned thr = pref;
  const unsigned neq_take = krem;
  unsigned cgt = 0, ceq = 0;
  for (int j = 0; j < 64; ++j) {
    unsigned u = __float_as_uint(p[t * 64 + j]);
    cgt += (u > thr);
    ceq += (u == thr);
  }
  sg[t] = cgt; sq[t] = ceq;
  __syncthreads();
  if (t == 0) {
    unsigned ag = 0, aq = 0;
    for (int i = 0; i < 256; ++i) {
      unsigned g = sg[i], q = sq[i];
      sg[i] = ag; sq[i] = aq;
      ag += g; aq += q;
    }
    bcast[2] = ag;  // n_gt
  }
  __syncthreads();
  const unsigned ngt = bcast[2];
  unsigned og = sg[t], oq = sq[t];
  int* oi = oidx + e * CAP;
  float* os = oscr + e * CAP;
  for (int j = 0; j < 64; ++j) {
    int tok = t * 64 + j;
    float pv = p[tok];
    unsigned u = __float_as_uint(pv);
    if (u > thr) {
      oi[og] = tok; os[og] = pv; ++og;
    } else if (u == thr) {
      if (oq < neq_take) { oi[ngt + oq] = tok; os[ngt + oq] = pv; }
      ++oq;
    }
  }
}

// ---------------- weight transpose + cvt: [R][C] f32 -> [C][R] bf16 ----------------
__global__ __launch_bounds__(256) void transpose_cvt(const float* __restrict__ in_e,
                                                     const float* __restrict__ in_s,
                                                     bf16* __restrict__ outp,
                                                     int R, int C) {
  int z = blockIdx.z;
  const float* in = (z < 8) ? (in_e + (size_t)z * (size_t)R * C) : in_s;
  bf16* out = outp + (size_t)z * (size_t)R * C;
  __shared__ float tile[64][65];
  int tx = threadIdx.x & 63, ty = threadIdx.x >> 6;
  int c0 = blockIdx.x * 64, r0 = blockIdx.y * 64;
  #pragma unroll
  for (int j = 0; j < 16; ++j) {
    int r = ty + j * 4;
    tile[r][tx] = in[(size_t)(r0 + r) * C + c0 + tx];
  }
  __syncthreads();
  #pragma unroll
  for (int j = 0; j < 16; ++j) {
    int c = ty + j * 4;
    out[(size_t)(c0 + c) * R + r0 + tx] = (bf16)tile[tx][c];
  }
}

// ---------------- FFN up GEMM: h = gelu(A @ W1 + b1), A rows gathered ----------------
// A: xb [NTOK][DMODEL] bf16 (rows via sel when routed). B: w1t [HFFN][DMODEL] bf16.
// 128x128 tile, BK=64, 4 waves, 16x16x32 bf16 MFMA, global_load_lds staging.
__global__ __launch_bounds__(256) void ffn1_gemm(const bf16* __restrict__ xb,
                                                 const bf16* __restrict__ w1t,
                                                 const float* __restrict__ bias1,
                                                 const int* __restrict__ sel,
                                                 bf16* __restrict__ hout,
                                                 int routed) {
  const int e = blockIdx.z;
  const bf16* Bw = w1t + (routed ? (size_t)e * HFFN * DMODEL : 0);
  const float* bias = bias1 + (routed ? (size_t)e * HFFN : 0);
  bf16* hb = hout + (routed ? (size_t)e * CAP * HFFN : 0);
  const int m0 = blockIdx.y * 128, n0 = blockIdx.x * 128;
  __shared__ __align__(16) bf16 smem[16384];  // As [128][64] | Bs [128][64]
  bf16* As = smem;
  bf16* Bs = smem + 8192;
  const int tid = threadIdx.x, lane = tid & 63, wave = tid >> 6;
  const int wr = wave >> 1, wc = wave & 1;
  const int rsub = tid >> 3, kch = tid & 7;
  const int* selE = routed ? (sel + e * CAP) : (const int*)nullptr;

  size_t rowA[4]; int rowB[4];
  #pragma unroll
  for (int r = 0; r < 4; ++r) {
    int mloc = rsub + 32 * r;
    int gr = routed ? selE[m0 + mloc] : (m0 + mloc);
    rowA[r] = (size_t)gr * DMODEL;
    rowB[r] = n0 + mloc;
  }
  f32x4 zero = {0.f, 0.f, 0.f, 0.f};
  f32x4 acc[4][4];
  #pragma unroll
  for (int i = 0; i < 4; ++i)
    #pragma unroll
    for (int j = 0; j < 4; ++j) acc[i][j] = zero;

  for (int k0 = 0; k0 < DMODEL; k0 += 64) {
    #pragma unroll
    for (int r = 0; r < 4; ++r)
      gload16(xb + rowA[r] + k0 + kch * 8, As + (r * 256 + wave * 64) * 8);
    #pragma unroll
    for (int r = 0; r < 4; ++r)
      gload16(Bw + (size_t)rowB[r] * DMODEL + k0 + kch * 8, Bs + (r * 256 + wave * 64) * 8);
    __syncthreads();
    #pragma unroll
    for (int ks = 0; ks < 2; ++ks) {
      const int kk = ks * 32 + (lane >> 4) * 8;
      bf16x8 av[4], bv[4];
      #pragma unroll
      for (int i = 0; i < 4; ++i) {
        av[i] = *(const bf16x8*)(As + (wr * 64 + i * 16 + (lane & 15)) * 64 + kk);
        bv[i] = *(const bf16x8*)(Bs + (wc * 64 + i * 16 + (lane & 15)) * 64 + kk);
      }
      #pragma unroll
      for (int i = 0; i < 4; ++i)
        #pragma unroll
        for (int j = 0; j < 4; ++j)
          acc[i][j] = __builtin_amdgcn_mfma_f32_16x16x32_bf16(av[i], bv[j], acc[i][j], 0, 0, 0);
    }
    __syncthreads();
  }

  // epilogue: bias + gelu -> bf16, LDS bounce for wide coalesced stores
  #pragma unroll
  for (int i = 0; i < 4; ++i) {
    #pragma unroll
    for (int j = 0; j < 4; ++j) {
      const int nl = wc * 64 + j * 16 + (lane & 15);
      const float b = bias[n0 + nl];
      #pragma unroll
      for (int q = 0; q < 4; ++q) {
        const int ml = wr * 64 + i * 16 + (lane >> 4) * 4 + q;
        smem[ml * 128 + nl] = (bf16)gelu_f(acc[i][j][q] + b);
      }
    }
  }
  __syncthreads();
  #pragma unroll
  for (int j = 0; j < 8; ++j) {
    const int c2 = tid + j * 256;
    const int ml = c2 >> 4, nc = (c2 & 15) * 8;
    uint4 v = *(const uint4*)(smem + c2 * 8);
    *(uint4*)(hb + (size_t)(m0 + ml) * HFFN + n0 + nc) = v;
  }
}

// ---------------- FFN down GEMM: y = h @ W2 + b2; store (shared) or atomic scatter (routed)
__global__ __launch_bounds__(256) void ffn2_gemm(const bf16* __restrict__ hbuf,
                                                 const bf16* __restrict__ w2t,
                                                 const float* __restrict__ bias2,
                                                 const int* __restrict__ sel,
                                                 const float* __restrict__ scr,
                                                 float* __restrict__ out,
                                                 int routed) {
  const int e = blockIdx.z;
  const bf16* Ab = hbuf + (routed ? (size_t)e * CAP * HFFN : 0);
  const bf16* Bw = w2t + (routed ? (size_t)e * DMODEL * HFFN : 0);
  const float* bias = bias2 + (routed ? (size_t)e * DMODEL : 0);
  const int m0 = blockIdx.y * 128, n0 = blockIdx.x * 128;
  __shared__ __align__(16) bf16 smem[16384];
  __shared__ int s_tok[128];
  __shared__ float s_scl[128];
  bf16* As = smem;
  bf16* Bs = smem + 8192;
  const int tid = threadIdx.x, lane = tid & 63, wave = tid >> 6;
  const int wr = wave >> 1, wc = wave & 1;
  const int rsub = tid >> 3, kch = tid & 7;
  if (routed && tid < 128) {
    s_tok[tid] = sel[e * CAP + m0 + tid];
    s_scl[tid] = scr[e * CAP + m0 + tid];
  }
  f32x4 zero = {0.f, 0.f, 0.f, 0.f};
  f32x4 acc[4][4];
  #pragma unroll
  for (int i = 0; i < 4; ++i)
    #pragma unroll
    for (int j = 0; j < 4; ++j) acc[i][j] = zero;

  for (int k0 = 0; k0 < HFFN; k0 += 64) {
    #pragma unroll
    for (int r = 0; r < 4; ++r) {
      int mloc = rsub + 32 * r;
      gload16(Ab + (size_t)(m0 + mloc) * HFFN + k0 + kch * 8, As + (r * 256 + wave * 64) * 8);
      gload16(Bw + (size_t)(n0 + mloc) * HFFN + k0 + kch * 8, Bs + (r * 256 + wave * 64) * 8);
    }
    __syncthreads();
    #pragma unroll
    for (int ks = 0; ks < 2; ++ks) {
      const int kk = ks * 32 + (lane >> 4) * 8;
      bf16x8 av[4], bv[4];
      #pragma unroll
      for (int i = 0; i < 4; ++i) {
        av[i] = *(const bf16x8*)(As + (wr * 64 + i * 16 + (lane & 15)) * 64 + kk);
        bv[i] = *(const bf16x8*)(Bs + (wc * 64 + i * 16 + (lane & 15)) * 64 + kk);
      }
      #pragma unroll
      for (int i = 0; i < 4; ++i)
        #pragma unroll
        for (int j = 0; j < 4; ++j)
          acc[i][j] = __builtin_amdgcn_mfma_f32_16x16x32_bf16(av[i], bv[j], acc[i][j], 0, 0, 0);
    }
    __syncthreads();
  }

  if (!routed) {
    #pragma unroll
    for (int i = 0; i < 4; ++i) {
      #pragma unroll
      for (int j = 0; j < 4; ++j) {
        const int nl = wc * 64 + j * 16 + (lane & 15);
        const float b = bias[n0 + nl];
        #pragma unroll
        for (int q = 0; q < 4; ++q) {
          const int ml = wr * 64 + i * 16 + (lane >> 4) * 4 + q;
          out[(size_t)(m0 + ml) * DMODEL + n0 + nl] = acc[i][j][q] + b;
        }
      }
    }
  } else {
    #pragma unroll
    for (int i = 0; i < 4; ++i) {
      #pragma unroll
      for (int j = 0; j < 4; ++j) {
        const int nl = wc * 64 + j * 16 + (lane & 15);
        const float b = bias[n0 + nl];
        #pragma unroll
        for (int q = 0; q < 4; ++q) {
          const int ml = wr * 64 + i * 16 + (lane >> 4) * 4 + q;
          const int tok = s_tok[ml];
          const float sc = s_scl[ml];
          atomicAdd(out + (size_t)tok * DMODEL + n0 + nl, (acc[i][j][q] + b) * sc);
        }
      }
    }
  }
}

extern "C" void kernel_launch(void* const* d_in, const int* in_sizes, int n_in,
                              void* d_out, int out_size, void* d_ws, size_t ws_size,
                              hipStream_t stream) {
  const float* x   = (const float*)d_in[0];
  const float* gw  = (const float*)d_in[1];
  const float* ew1 = (const float*)d_in[2];
  const float* eb1 = (const float*)d_in[3];
  const float* ew2 = (const float*)d_in[4];
  const float* eb2 = (const float*)d_in[5];
  const float* sw1 = (const float*)d_in[6];
  const float* sb1 = (const float*)d_in[7];
  const float* sw2 = (const float*)d_in[8];
  const float* sb2 = (const float*)d_in[9];
  float* out = (float*)d_out;

  char* ws = (char*)d_ws;
  size_t off = 0;
  bf16* xb      = (bf16*)(ws + off); off += (size_t)NTOK * DMODEL * 2;      // 32 MiB
  bf16* w1t     = (bf16*)(ws + off); off += (size_t)9 * HFFN * DMODEL * 2;  // 72 MiB ([e<8]=ew1t, [8]=sw1t)
  bf16* w2t     = (bf16*)(ws + off); off += (size_t)9 * DMODEL * HFFN * 2;  // 72 MiB
  bf16* hbuf    = (bf16*)(ws + off); off += (size_t)NTOK * HFFN * 2;        // 128 MiB (reused shared->routed)
  float* probs  = (float*)(ws + off); off += (size_t)NEXP * NTOK * 4;
  int* selidx   = (int*)(ws + off);   off += (size_t)NEXP * CAP * 4;
  float* selscr = (float*)(ws + off); off += (size_t)NEXP * CAP * 4;
  // total ~305 MiB

  cvt_x_kernel<<<dim3(NTOK * DMODEL / 8 / 256), dim3(256), 0, stream>>>(x, xb);
  router_kernel<<<dim3(NTOK), dim3(64), 0, stream>>>(x, gw, probs);
  topk_kernel<<<dim3(NEXP), dim3(256), 0, stream>>>(probs, selidx, selscr);
  transpose_cvt<<<dim3(HFFN / 64, DMODEL / 64, 9), dim3(256), 0, stream>>>(ew1, sw1, w1t, DMODEL, HFFN);
  transpose_cvt<<<dim3(DMODEL / 64, HFFN / 64, 9), dim3(256), 0, stream>>>(ew2, sw2, w2t, HFFN, DMODEL);

  // shared expert over all tokens: writes every out element (no zero-init needed)
  ffn1_gemm<<<dim3(HFFN / 128, NTOK / 128, 1), dim3(256), 0, stream>>>(
      xb, w1t + (size_t)8 * HFFN * DMODEL, sb1, (const int*)nullptr, hbuf, 0);
  ffn2_gemm<<<dim3(DMODEL / 128, NTOK / 128, 1), dim3(256), 0, stream>>>(
      hbuf, w2t + (size_t)8 * DMODEL * HFFN, sb2, (const int*)nullptr, (const float*)nullptr, out, 0);

  // routed experts: gather via selidx, scatter-add scaled by score
  ffn1_gemm<<<dim3(HFFN / 128, CAP / 128, NEXP), dim3(256), 0, stream>>>(
      xb, w1t, eb1, selidx, hbuf, 1);
  ffn2_gemm<<<dim3(DMODEL / 128, CAP / 128, NEXP), dim3(256), 0, stream>>>(
      hbuf, w2t, eb2, selidx, selscr, out, 1);
}

// Round 2
// 1087.288 us; speedup vs baseline: 1.0809x; 1.0809x over previous
//
#include <hip/hip_runtime.h>

typedef __bf16 bf16;
typedef __bf16 bf16x8 __attribute__((ext_vector_type(8)));
typedef float f32x4 __attribute__((ext_vector_type(4)));

#define NTOK 16384
#define DMODEL 1024
#define HFFN 4096
#define NEXP 8
#define CAP 2048

__device__ __forceinline__ void gload16(const void* g, void* l) {
  __builtin_amdgcn_global_load_lds((const __attribute__((address_space(1))) void*)g,
                                   (__attribute__((address_space(3))) void*)l, 16, 0, 0);
}

__device__ __forceinline__ float gelu_f(float v) {
  float u = 0.7978845608028654f * (v + 0.044715f * v * v * v);
  float ex = __expf(2.0f * u);
  float th = 1.0f - 2.0f / (ex + 1.0f);
  return 0.5f * v * (1.0f + th);
}

// ---------------- x: f32 -> bf16 ----------------
__global__ __launch_bounds__(256) void cvt_x_kernel(const float* __restrict__ x,
                                                    bf16* __restrict__ xb) {
  int i = blockIdx.x * blockDim.x + threadIdx.x;
  const float4* a = (const float4*)x + (size_t)i * 2;
  float4 v0 = a[0], v1 = a[1];
  bf16x8 o;
  o[0]=(bf16)v0.x; o[1]=(bf16)v0.y; o[2]=(bf16)v0.z; o[3]=(bf16)v0.w;
  o[4]=(bf16)v1.x; o[5]=(bf16)v1.y; o[6]=(bf16)v1.z; o[7]=(bf16)v1.w;
  *(bf16x8*)(xb + (size_t)i * 8) = o;
}

// ---------------- router: probs[e][t] ----------------
__global__ __launch_bounds__(64) void router_kernel(const float* __restrict__ x,
                                                    const float* __restrict__ gw,
                                                    float* __restrict__ probs) {
  int t = blockIdx.x;
  int l = threadIdx.x;
  int e = l & 7, chunk = l >> 3;
  const float* xr = x + (size_t)t * DMODEL + chunk * 128;
  const float* gwr = gw + (size_t)(chunk * 128) * NEXP + e;
  float a0 = 0.f, a1 = 0.f;
  #pragma unroll
  for (int d = 0; d < 128; d += 8) {
    float4 xv = *(const float4*)(xr + d);
    float4 xw = *(const float4*)(xr + d + 4);
    a0 += xv.x * gwr[(d+0)*8] + xv.y * gwr[(d+1)*8] + xv.z * gwr[(d+2)*8] + xv.w * gwr[(d+3)*8];
    a1 += xw.x * gwr[(d+4)*8] + xw.y * gwr[(d+5)*8] + xw.z * gwr[(d+6)*8] + xw.w * gwr[(d+7)*8];
  }
  float acc = a0 + a1;
  acc += __shfl_xor(acc, 8);
  acc += __shfl_xor(acc, 16);
  acc += __shfl_xor(acc, 32);
  float m = acc;
  m = fmaxf(m, __shfl_xor(m, 1));
  m = fmaxf(m, __shfl_xor(m, 2));
  m = fmaxf(m, __shfl_xor(m, 4));
  float ex = expf(acc - m);
  float s = ex;
  s += __shfl_xor(s, 1); s += __shfl_xor(s, 2); s += __shfl_xor(s, 4);
  if (l < 8) probs[(size_t)e * NTOK + t] = ex / s;
}

// ---------------- per-expert top-2048 radix select ----------------
__global__ __launch_bounds__(256) void topk_kernel(const float* __restrict__ probs,
                                                   int* __restrict__ oidx,
                                                   float* __restrict__ oscr) {
  const int e = blockIdx.x;
  const float* p = probs + (size_t)e * NTOK;
  const int t = threadIdx.x;
  __shared__ unsigned hist[256];
  __shared__ unsigned sg[256], sq[256];
  __shared__ unsigned bcast[4];
  unsigned pref = 0, krem = CAP;
  for (int pass = 0; pass < 4; ++pass) {
    const int sh = 24 - pass * 8;
    hist[t] = 0;
    __syncthreads();
    for (int j = 0; j < 64; ++j) {
      unsigned u = __float_as_uint(p[t * 64 + j]);
      bool ok = (pass == 0) || ((u >> (sh + 8)) == pref);
      if (ok) atomicAdd(&hist[(u >> sh) & 255u], 1u);
    }
    __syncthreads();
    if (t == 0) {
      unsigned cum = 0; int b = 255;
      for (; b > 0; --b) {
        unsigned c = hist[b];
        if (cum + c >= krem) break;
        cum += c;
      }
      bcast[0] = (pref << 8) | (unsigned)b;
      bcast[1] = krem - cum;
    }
    __syncthreads();
    pref = bcast[0];
    krem = bcast[1];
  }
  const unsigned thr = pref;
  const unsigned neq_take = krem;
  unsigned cgt = 0, ceq = 0;
  for (int j = 0; j < 64; ++j) {
    unsigned u = __float_as_uint(p[t * 64 + j]);
    cgt += (u > thr);
    ceq += (u == thr);
  }
  sg[t] = cgt; sq[t] = ceq;
  __syncthreads();
  if (t == 0) {
    unsigned ag = 0, aq = 0;
    for (int i = 0; i < 256; ++i) {
      unsigned g = sg[i], q = sq[i];
      sg[i] = ag; sq[i] = aq;
      ag += g; aq += q;
    }
    bcast[2] = ag;
  }
  __syncthreads();
  const unsigned ngt = bcast[2];
  unsigned og = sg[t], oq = sq[t];
  int* oi = oidx + e * CAP;
  float* os = oscr + e * CAP;
  for (int j = 0; j < 64; ++j) {
    int tok = t * 64 + j;
    float pv = p[tok];
    unsigned u = __float_as_uint(pv);
    if (u > thr) {
      oi[og] = tok; os[og] = pv; ++og;
    } else if (u == thr) {
      if (oq < neq_take) { oi[ngt + oq] = tok; os[ngt + oq] = pv; }
      ++oq;
    }
  }
}

// ---------------- weight transpose + cvt: [R][C] f32 -> [C][R] bf16 ----------------
__global__ __launch_bounds__(256) void transpose_cvt(const float* __restrict__ in_e,
                                                     const float* __restrict__ in_s,
                                                     bf16* __restrict__ outp,
                                                     int R, int C) {
  int z = blockIdx.z;
  const float* in = (z < 8) ? (in_e + (size_t)z * (size_t)R * C) : in_s;
  bf16* out = outp + (size_t)z * (size_t)R * C;
  __shared__ float tile[64][65];
  int tx = threadIdx.x & 63, ty = threadIdx.x >> 6;
  int c0 = blockIdx.x * 64, r0 = blockIdx.y * 64;
  #pragma unroll
  for (int j = 0; j < 16; ++j) {
    int r = ty + j * 4;
    tile[r][tx] = in[(size_t)(r0 + r) * C + c0 + tx];
  }
  __syncthreads();
  #pragma unroll
  for (int j = 0; j < 16; ++j) {
    int c = ty + j * 4;
    out[(size_t)(c0 + c) * R + r0 + tx] = (bf16)tile[tx][c];
  }
}

// ---------------- FFN up GEMM (swizzled LDS) ----------------
// LDS holds, at (row, chunk), global data (row, chunk ^ (row&7)); chunks are 16B.
// Source-side: lane fetches chunk kch^(row&7). Read-side: same XOR (involution).
__global__ __launch_bounds__(256) void ffn1_gemm(const bf16* __restrict__ xb,
                                                 const bf16* __restrict__ w1t,
                                                 const float* __restrict__ bias1,
                                                 const int* __restrict__ sel,
                                                 bf16* __restrict__ hout,
                                                 int routed) {
  const int e = blockIdx.z;
  const bf16* Bw = w1t + (routed ? (size_t)e * HFFN * DMODEL : 0);
  const float* bias = bias1 + (routed ? (size_t)e * HFFN : 0);
  bf16* hb = hout + (routed ? (size_t)e * CAP * HFFN : 0);
  const int m0 = blockIdx.y * 128, n0 = blockIdx.x * 128;
  __shared__ __align__(16) bf16 smem[16384];
  bf16* As = smem;
  bf16* Bs = smem + 8192;
  const int tid = threadIdx.x, lane = tid & 63, wave = tid >> 6;
  const int wr = wave >> 1, wc = wave & 1;
  const int rsub = tid >> 3, kch = tid & 7;
  const int kchs = kch ^ (rsub & 7);   // swizzled source chunk
  const int* selE = routed ? (sel + e * CAP) : (const int*)nullptr;

  size_t rowA[4]; int rowB[4];
  #pragma unroll
  for (int r = 0; r < 4; ++r) {
    int mloc = rsub + 32 * r;
    int gr = routed ? selE[m0 + mloc] : (m0 + mloc);
    rowA[r] = (size_t)gr * DMODEL;
    rowB[r] = n0 + mloc;
  }
  f32x4 zero = {0.f, 0.f, 0.f, 0.f};
  f32x4 acc[4][4];
  #pragma unroll
  for (int i = 0; i < 4; ++i)
    #pragma unroll
    for (int j = 0; j < 4; ++j) acc[i][j] = zero;

  for (int k0 = 0; k0 < DMODEL; k0 += 64) {
    #pragma unroll
    for (int r = 0; r < 4; ++r)
      gload16(xb + rowA[r] + k0 + kchs * 8, As + (r * 256 + wave * 64) * 8);
    #pragma unroll
    for (int r = 0; r < 4; ++r)
      gload16(Bw + (size_t)rowB[r] * DMODEL + k0 + kchs * 8, Bs + (r * 256 + wave * 64) * 8);
    __syncthreads();
    #pragma unroll
    for (int ks = 0; ks < 2; ++ks) {
      const int kkc = ((ks * 4 + (lane >> 4)) ^ (lane & 7)) * 8;  // swizzled read chunk
      bf16x8 av[4], bv[4];
      #pragma unroll
      for (int i = 0; i < 4; ++i) {
        av[i] = *(const bf16x8*)(As + (wr * 64 + i * 16 + (lane & 15)) * 64 + kkc);
        bv[i] = *(const bf16x8*)(Bs + (wc * 64 + i * 16 + (lane & 15)) * 64 + kkc);
      }
      #pragma unroll
      for (int i = 0; i < 4; ++i)
        #pragma unroll
        for (int j = 0; j < 4; ++j)
          acc[i][j] = __builtin_amdgcn_mfma_f32_16x16x32_bf16(av[i], bv[j], acc[i][j], 0, 0, 0);
    }
    __syncthreads();
  }

  // epilogue: bias + gelu -> bf16, swizzled LDS bounce (key = (ml>>2)&7 on 32B slots)
  #pragma unroll
  for (int i = 0; i < 4; ++i) {
    #pragma unroll
    for (int j = 0; j < 4; ++j) {
      const int nl = wc * 64 + j * 16 + (lane & 15);
      const float b = bias[n0 + nl];
      #pragma unroll
      for (int q = 0; q < 4; ++q) {
        const int ml = wr * 64 + i * 16 + (lane >> 4) * 4 + q;
        const int el = nl ^ (((ml >> 2) & 7) << 4);
        smem[ml * 128 + el] = (bf16)gelu_f(acc[i][j][q] + b);
      }
    }
  }
  __syncthreads();
  #pragma unroll
  for (int j = 0; j < 8; ++j) {
    const int c2 = tid + j * 256;
    const int ml = c2 >> 4, nc8 = c2 & 15;
    const int el = (nc8 * 8) ^ (((ml >> 2) & 7) << 4);
    uint4 v = *(const uint4*)(smem + ml * 128 + el);
    *(uint4*)(hb + (size_t)(m0 + ml) * HFFN + n0 + nc8 * 8) = v;
  }
}

// ---------------- FFN down GEMM (swizzled LDS) ----------------
__global__ __launch_bounds__(256) void ffn2_gemm(const bf16* __restrict__ hbuf,
                                                 const bf16* __restrict__ w2t,
                                                 const float* __restrict__ bias2,
                                                 const int* __restrict__ sel,
                                                 const float* __restrict__ scr,
                                                 float* __restrict__ out,
                                                 int routed) {
  const int e = blockIdx.z;
  const bf16* Ab = hbuf + (routed ? (size_t)e * CAP * HFFN : 0);
  const bf16* Bw = w2t + (routed ? (size_t)e * DMODEL * HFFN : 0);
  const float* bias = bias2 + (routed ? (size_t)e * DMODEL : 0);
  const int m0 = blockIdx.y * 128, n0 = blockIdx.x * 128;
  __shared__ __align__(16) bf16 smem[16384];
  __shared__ int s_tok[128];
  __shared__ float s_scl[128];
  bf16* As = smem;
  bf16* Bs = smem + 8192;
  const int tid = threadIdx.x, lane = tid & 63, wave = tid >> 6;
  const int wr = wave >> 1, wc = wave & 1;
  const int rsub = tid >> 3, kch = tid & 7;
  const int kchs = kch ^ (rsub & 7);
  if (routed && tid < 128) {
    s_tok[tid] = sel[e * CAP + m0 + tid];
    s_scl[tid] = scr[e * CAP + m0 + tid];
  }
  f32x4 zero = {0.f, 0.f, 0.f, 0.f};
  f32x4 acc[4][4];
  #pragma unroll
  for (int i = 0; i < 4; ++i)
    #pragma unroll
    for (int j = 0; j < 4; ++j) acc[i][j] = zero;

  for (int k0 = 0; k0 < HFFN; k0 += 64) {
    #pragma unroll
    for (int r = 0; r < 4; ++r) {
      int mloc = rsub + 32 * r;
      gload16(Ab + (size_t)(m0 + mloc) * HFFN + k0 + kchs * 8, As + (r * 256 + wave * 64) * 8);
      gload16(Bw + (size_t)(n0 + mloc) * HFFN + k0 + kchs * 8, Bs + (r * 256 + wave * 64) * 8);
    }
    __syncthreads();
    #pragma unroll
    for (int ks = 0; ks < 2; ++ks) {
      const int kkc = ((ks * 4 + (lane >> 4)) ^ (lane & 7)) * 8;
      bf16x8 av[4], bv[4];
      #pragma unroll
      for (int i = 0; i < 4; ++i) {
        av[i] = *(const bf16x8*)(As + (wr * 64 + i * 16 + (lane & 15)) * 64 + kkc);
        bv[i] = *(const bf16x8*)(Bs + (wc * 64 + i * 16 + (lane & 15)) * 64 + kkc);
      }
      #pragma unroll
      for (int i = 0; i < 4; ++i)
        #pragma unroll
        for (int j = 0; j < 4; ++j)
          acc[i][j] = __builtin_amdgcn_mfma_f32_16x16x32_bf16(av[i], bv[j], acc[i][j], 0, 0, 0);
    }
    __syncthreads();
  }

  if (!routed) {
    #pragma unroll
    for (int i = 0; i < 4; ++i) {
      #pragma unroll
      for (int j = 0; j < 4; ++j) {
        const int nl = wc * 64 + j * 16 + (lane & 15);
        const float b = bias[n0 + nl];
        #pragma unroll
        for (int q = 0; q < 4; ++q) {
          const int ml = wr * 64 + i * 16 + (lane >> 4) * 4 + q;
          out[(size_t)(m0 + ml) * DMODEL + n0 + nl] = acc[i][j][q] + b;
        }
      }
    }
  } else {
    #pragma unroll
    for (int i = 0; i < 4; ++i) {
      #pragma unroll
      for (int j = 0; j < 4; ++j) {
        const int nl = wc * 64 + j * 16 + (lane & 15);
        const float b = bias[n0 + nl];
        #pragma unroll
        for (int q = 0; q < 4; ++q) {
          const int ml = wr * 64 + i * 16 + (lane >> 4) * 4 + q;
          const int tok = s_tok[ml];
          const float sc = s_scl[ml];
          atomicAdd(out + (size_t)tok * DMODEL + n0 + nl, (acc[i][j][q] + b) * sc);
        }
      }
    }
  }
}

extern "C" void kernel_launch(void* const* d_in, const int* in_sizes, int n_in,
                              void* d_out, int out_size, void* d_ws, size_t ws_size,
                              hipStream_t stream) {
  const float* x   = (const float*)d_in[0];
  const float* gw  = (const float*)d_in[1];
  const float* ew1 = (const float*)d_in[2];
  const float* eb1 = (const float*)d_in[3];
  const float* ew2 = (const float*)d_in[4];
  const float* eb2 = (const float*)d_in[5];
  const float* sw1 = (const float*)d_in[6];
  const float* sb1 = (const float*)d_in[7];
  const float* sw2 = (const float*)d_in[8];
  const float* sb2 = (const float*)d_in[9];
  float* out = (float*)d_out;

  char* ws = (char*)d_ws;
  size_t off = 0;
  bf16* xb      = (bf16*)(ws + off); off += (size_t)NTOK * DMODEL * 2;
  bf16* w1t     = (bf16*)(ws + off); off += (size_t)9 * HFFN * DMODEL * 2;
  bf16* w2t     = (bf16*)(ws + off); off += (size_t)9 * DMODEL * HFFN * 2;
  bf16* hbuf    = (bf16*)(ws + off); off += (size_t)NTOK * HFFN * 2;
  float* probs  = (float*)(ws + off); off += (size_t)NEXP * NTOK * 4;
  int* selidx   = (int*)(ws + off);   off += (size_t)NEXP * CAP * 4;
  float* selscr = (float*)(ws + off); off += (size_t)NEXP * CAP * 4;

  cvt_x_kernel<<<dim3(NTOK * DMODEL / 8 / 256), dim3(256), 0, stream>>>(x, xb);
  router_kernel<<<dim3(NTOK), dim3(64), 0, stream>>>(x, gw, probs);
  topk_kernel<<<dim3(NEXP), dim3(256), 0, stream>>>(probs, selidx, selscr);
  transpose_cvt<<<dim3(HFFN / 64, DMODEL / 64, 9), dim3(256), 0, stream>>>(ew1, sw1, w1t, DMODEL, HFFN);
  transpose_cvt<<<dim3(DMODEL / 64, HFFN / 64, 9), dim3(256), 0, stream>>>(ew2, sw2, w2t, HFFN, DMODEL);

  ffn1_gemm<<<dim3(HFFN / 128, NTOK / 128, 1), dim3(256), 0, stream>>>(
      xb, w1t + (size_t)8 * HFFN * DMODEL, sb1, (const int*)nullptr, hbuf, 0);
  ffn2_gemm<<<dim3(DMODEL / 128, NTOK / 128, 1), dim3(256), 0, stream>>>(
      hbuf, w2t + (size_t)8 * DMODEL * HFFN, sb2, (const int*)nullptr, (const float*)nullptr, out, 0);

  ffn1_gemm<<<dim3(HFFN / 128, CAP / 128, NEXP), dim3(256), 0, stream>>>(
      xb, w1t, eb1, selidx, hbuf, 1);
  ffn2_gemm<<<dim3(DMODEL / 128, CAP / 128, NEXP), dim3(256), 0, stream>>>(
      hbuf, w2t, eb2, selidx, selscr, out, 1);
}

// Round 3
// 1023.190 us; speedup vs baseline: 1.1487x; 1.0626x over previous
//
#include <hip/hip_runtime.h>

typedef __bf16 bf16;
typedef __bf16 bf16x8 __attribute__((ext_vector_type(8)));
typedef float f32x4 __attribute__((ext_vector_type(4)));

#define NTOK 16384
#define DMODEL 1024
#define HFFN 4096
#define NEXP 8
#define CAP 2048

#define VMCNT(n) asm volatile("s_waitcnt vmcnt(" #n ")" ::: "memory")
#define RAWBAR() do { __builtin_amdgcn_s_barrier(); __builtin_amdgcn_sched_barrier(0); } while (0)

__device__ __forceinline__ void gload16(const void* g, void* l) {
  __builtin_amdgcn_global_load_lds((const __attribute__((address_space(1))) void*)g,
                                   (__attribute__((address_space(3))) void*)l, 16, 0, 0);
}

__device__ __forceinline__ float gelu_f(float v) {
  float u = 0.7978845608028654f * (v + 0.044715f * v * v * v);
  float ex = __expf(2.0f * u);
  float th = 1.0f - 2.0f / (ex + 1.0f);
  return 0.5f * v * (1.0f + th);
}

// ---------------- x: f32 -> bf16 ----------------
__global__ __launch_bounds__(256) void cvt_x_kernel(const float* __restrict__ x,
                                                    bf16* __restrict__ xb) {
  int i = blockIdx.x * blockDim.x + threadIdx.x;
  const float4* a = (const float4*)x + (size_t)i * 2;
  float4 v0 = a[0], v1 = a[1];
  bf16x8 o;
  o[0]=(bf16)v0.x; o[1]=(bf16)v0.y; o[2]=(bf16)v0.z; o[3]=(bf16)v0.w;
  o[4]=(bf16)v1.x; o[5]=(bf16)v1.y; o[6]=(bf16)v1.z; o[7]=(bf16)v1.w;
  *(bf16x8*)(xb + (size_t)i * 8) = o;
}

// ---------------- router ----------------
__global__ __launch_bounds__(64) void router_kernel(const float* __restrict__ x,
                                                    const float* __restrict__ gw,
                                                    float* __restrict__ probs) {
  int t = blockIdx.x;
  int l = threadIdx.x;
  int e = l & 7, chunk = l >> 3;
  const float* xr = x + (size_t)t * DMODEL + chunk * 128;
  const float* gwr = gw + (size_t)(chunk * 128) * NEXP + e;
  float a0 = 0.f, a1 = 0.f;
  #pragma unroll
  for (int d = 0; d < 128; d += 8) {
    float4 xv = *(const float4*)(xr + d);
    float4 xw = *(const float4*)(xr + d + 4);
    a0 += xv.x * gwr[(d+0)*8] + xv.y * gwr[(d+1)*8] + xv.z * gwr[(d+2)*8] + xv.w * gwr[(d+3)*8];
    a1 += xw.x * gwr[(d+4)*8] + xw.y * gwr[(d+5)*8] + xw.z * gwr[(d+6)*8] + xw.w * gwr[(d+7)*8];
  }
  float acc = a0 + a1;
  acc += __shfl_xor(acc, 8);
  acc += __shfl_xor(acc, 16);
  acc += __shfl_xor(acc, 32);
  float m = acc;
  m = fmaxf(m, __shfl_xor(m, 1));
  m = fmaxf(m, __shfl_xor(m, 2));
  m = fmaxf(m, __shfl_xor(m, 4));
  float ex = expf(acc - m);
  float s = ex;
  s += __shfl_xor(s, 1); s += __shfl_xor(s, 2); s += __shfl_xor(s, 4);
  if (l < 8) probs[(size_t)e * NTOK + t] = ex / s;
}

// ---------------- per-expert top-2048 radix select ----------------
__global__ __launch_bounds__(256) void topk_kernel(const float* __restrict__ probs,
                                                   int* __restrict__ oidx,
                                                   float* __restrict__ oscr) {
  const int e = blockIdx.x;
  const float* p = probs + (size_t)e * NTOK;
  const int t = threadIdx.x;
  __shared__ unsigned hist[256];
  __shared__ unsigned sg[256], sq[256];
  __shared__ unsigned bcast[4];
  unsigned pref = 0, krem = CAP;
  for (int pass = 0; pass < 4; ++pass) {
    const int sh = 24 - pass * 8;
    hist[t] = 0;
    __syncthreads();
    for (int j = 0; j < 64; ++j) {
      unsigned u = __float_as_uint(p[t * 64 + j]);
      bool ok = (pass == 0) || ((u >> (sh + 8)) == pref);
      if (ok) atomicAdd(&hist[(u >> sh) & 255u], 1u);
    }
    __syncthreads();
    if (t == 0) {
      unsigned cum = 0; int b = 255;
      for (; b > 0; --b) {
        unsigned c = hist[b];
        if (cum + c >= krem) break;
        cum += c;
      }
      bcast[0] = (pref << 8) | (unsigned)b;
      bcast[1] = krem - cum;
    }
    __syncthreads();
    pref = bcast[0];
    krem = bcast[1];
  }
  const unsigned thr = pref;
  const unsigned neq_take = krem;
  unsigned cgt = 0, ceq = 0;
  for (int j = 0; j < 64; ++j) {
    unsigned u = __float_as_uint(p[t * 64 + j]);
    cgt += (u > thr);
    ceq += (u == thr);
  }
  sg[t] = cgt; sq[t] = ceq;
  __syncthreads();
  if (t == 0) {
    unsigned ag = 0, aq = 0;
    for (int i = 0; i < 256; ++i) {
      unsigned g = sg[i], q = sq[i];
      sg[i] = ag; sq[i] = aq;
      ag += g; aq += q;
    }
    bcast[2] = ag;
  }
  __syncthreads();
  const unsigned ngt = bcast[2];
  unsigned og = sg[t], oq = sq[t];
  int* oi = oidx + e * CAP;
  float* os = oscr + e * CAP;
  for (int j = 0; j < 64; ++j) {
    int tok = t * 64 + j;
    float pv = p[tok];
    unsigned u = __float_as_uint(pv);
    if (u > thr) {
      oi[og] = tok; os[og] = pv; ++og;
    } else if (u == thr) {
      if (oq < neq_take) { oi[ngt + oq] = tok; os[ngt + oq] = pv; }
      ++oq;
    }
  }
}

// ---------------- weight transpose + cvt ----------------
__global__ __launch_bounds__(256) void transpose_cvt(const float* __restrict__ in_e,
                                                     const float* __restrict__ in_s,
                                                     bf16* __restrict__ outp,
                                                     int R, int C) {
  int z = blockIdx.z;
  const float* in = (z < 8) ? (in_e + (size_t)z * (size_t)R * C) : in_s;
  bf16* out = outp + (size_t)z * (size_t)R * C;
  __shared__ float tile[64][65];
  int tx = threadIdx.x & 63, ty = threadIdx.x >> 6;
  int c0 = blockIdx.x * 64, r0 = blockIdx.y * 64;
  #pragma unroll
  for (int j = 0; j < 16; ++j) {
    int r = ty + j * 4;
    tile[r][tx] = in[(size_t)(r0 + r) * C + c0 + tx];
  }
  __syncthreads();
  #pragma unroll
  for (int j = 0; j < 16; ++j) {
    int c = ty + j * 4;
    out[(size_t)(c0 + c) * R + r0 + tx] = (bf16)tile[tx][c];
  }
}

// =====================================================================
// 256x256 tile, BK=32, 512 threads (8 waves of 128x64), triple-buffered
// LDS ring with counted vmcnt (never drained to 0 in steady state).
// Buffer b read at iter t is re-staged at iter t+1 (issue strictly after
// the barrier following all reads) -> race-free by construction.
// LDS per buffer: A 256x32 + B 256x32 bf16 = 32 KiB; 3 buffers = 96 KiB.
// T2 swizzle: LDS (row, c) holds global (row, c ^ (row&3)), c = 16B chunk.
// =====================================================================

// ---------------- FFN up GEMM: h = gelu(A @ W1^T + b1) ----------------
__global__ __launch_bounds__(512, 2) void ffn1_gemm(const bf16* __restrict__ xb,
                                                    const bf16* __restrict__ w1t,
                                                    const float* __restrict__ bias1,
                                                    const int* __restrict__ sel,
                                                    bf16* __restrict__ hout,
                                                    int routed) {
  const int e = blockIdx.z;
  const bf16* Bw = w1t + (routed ? (size_t)e * HFFN * DMODEL : 0);
  const float* bias = bias1 + (routed ? (size_t)e * HFFN : 0);
  bf16* hb = hout + (routed ? (size_t)e * CAP * HFFN : 0);
  const int m0 = blockIdx.y * 256, n0 = blockIdx.x * 256;
  __shared__ __align__(16) bf16 smem[49152];   // 96 KiB: 3 x (A 8192 | B 8192)
  const int tid = threadIdx.x, lane = tid & 63, wave = tid >> 6;
  const int wr = wave >> 2, wc = wave & 3;

  // staging: per gload, 512 threads cover 128 rows x 4 chunks(16B)
  const int srow = tid >> 2, sch = tid & 3;
  const int schs = sch ^ (srow & 3);           // source-side swizzle
  const int ldst = srow * 32 + sch * 8;        // LDS dest (bf16), linear
  const bf16 *srcA0, *srcA1, *srcB0, *srcB1;
  {
    int r0i = routed ? sel[e * CAP + m0 + srow] : (m0 + srow);
    int r1i = routed ? sel[e * CAP + m0 + 128 + srow] : (m0 + 128 + srow);
    srcA0 = xb + (size_t)r0i * DMODEL + schs * 8;
    srcA1 = xb + (size_t)r1i * DMODEL + schs * 8;
    srcB0 = Bw + (size_t)(n0 + srow) * DMODEL + schs * 8;
    srcB1 = Bw + (size_t)(n0 + 128 + srow) * DMODEL + schs * 8;
  }

  f32x4 acc[8][4];
  #pragma unroll
  for (int i = 0; i < 8; ++i)
    #pragma unroll
    for (int j = 0; j < 4; ++j) acc[i][j] = (f32x4){0.f, 0.f, 0.f, 0.f};

  const int fr = lane & 15;
  const int fch = ((lane >> 4) ^ (lane & 3)) * 8;  // read-side swizzled chunk
  const int NT = DMODEL / 32;

  #define STAGE1(t, b) do { \
    bf16* As_ = smem + (b) * 16384; \
    const int ko = (t) * 32; \
    gload16(srcA0 + ko, As_ + ldst); \
    gload16(srcA1 + ko, As_ + 4096 + ldst); \
    gload16(srcB0 + ko, As_ + 8192 + ldst); \
    gload16(srcB1 + ko, As_ + 12288 + ldst); \
  } while (0)

  STAGE1(0, 0);
  STAGE1(1, 1);
  VMCNT(4);
  RAWBAR();

  int b = 0;
  for (int t = 0; t < NT; ++t) {
    int b2 = b + 2; if (b2 >= 3) b2 -= 3;
    if (t + 2 < NT) STAGE1(t + 2, b2);
    const bf16* As = smem + b * 16384;
    const bf16* Bs = As + 8192;
    bf16x8 av[8], bv[4];
    #pragma unroll
    for (int i = 0; i < 8; ++i)
      av[i] = *(const bf16x8*)(As + (wr * 128 + i * 16 + fr) * 32 + fch);
    #pragma unroll
    for (int j = 0; j < 4; ++j)
      bv[j] = *(const bf16x8*)(Bs + (wc * 64 + j * 16 + fr) * 32 + fch);
    __builtin_amdgcn_s_setprio(1);
    #pragma unroll
    for (int i = 0; i < 8; ++i)
      #pragma unroll
      for (int j = 0; j < 4; ++j)
        acc[i][j] = __builtin_amdgcn_mfma_f32_16x16x32_bf16(av[i], bv[j], acc[i][j], 0, 0, 0);
    __builtin_amdgcn_s_setprio(0);
    if (t + 2 < NT) { VMCNT(4); } else { VMCNT(0); }
    RAWBAR();
    if (++b == 3) b = 0;
  }
  #undef STAGE1

  // epilogue: bias+gelu -> bf16, two 128-row halves through swizzled LDS bounce
  #pragma unroll
  for (int half = 0; half < 2; ++half) {
    if (wr == half) {
      #pragma unroll
      for (int i = 0; i < 8; ++i) {
        #pragma unroll
        for (int j = 0; j < 4; ++j) {
          const int nl = wc * 64 + j * 16 + fr;
          const float bb = bias[n0 + nl];
          #pragma unroll
          for (int q = 0; q < 4; ++q) {
            const int ml = i * 16 + (lane >> 4) * 4 + q;   // 0..127 in half
            smem[ml * 256 + (nl ^ (((ml >> 2) & 7) << 4))] =
                (bf16)gelu_f(acc[i][j][q] + bb);
          }
        }
      }
    }
    __syncthreads();
    #pragma unroll
    for (int p = 0; p < 8; ++p) {
      const int flat = p * 512 + tid;
      const int row = flat >> 5, nc8 = flat & 31;
      uint4 v = *(const uint4*)(smem + row * 256 + ((nc8 * 8) ^ (((row >> 2) & 7) << 4)));
      *(uint4*)(hb + (size_t)(m0 + half * 128 + row) * HFFN + n0 + nc8 * 8) = v;
    }
    __syncthreads();
  }
}

// ---------------- FFN down GEMM: y = h @ W2^T + b2 ----------------
__global__ __launch_bounds__(512, 2) void ffn2_gemm(const bf16* __restrict__ hbuf,
                                                    const bf16* __restrict__ w2t,
                                                    const float* __restrict__ bias2,
                                                    const int* __restrict__ sel,
                                                    const float* __restrict__ scr,
                                                    float* __restrict__ out,
                                                    int routed) {
  const int e = blockIdx.z;
  const bf16* Ab = hbuf + (routed ? (size_t)e * CAP * HFFN : 0);
  const bf16* Bw = w2t + (routed ? (size_t)e * DMODEL * HFFN : 0);
  const float* bias = bias2 + (routed ? (size_t)e * DMODEL : 0);
  const int m0 = blockIdx.y * 256, n0 = blockIdx.x * 256;
  __shared__ __align__(16) bf16 smem[49152];
  __shared__ int s_tok[256];
  __shared__ float s_scl[256];
  const int tid = threadIdx.x, lane = tid & 63, wave = tid >> 6;
  const int wr = wave >> 2, wc = wave & 3;

  const int srow = tid >> 2, sch = tid & 3;
  const int schs = sch ^ (srow & 3);
  const int ldst = srow * 32 + sch * 8;
  const bf16* srcA0 = Ab + (size_t)(m0 + srow) * HFFN + schs * 8;
  const bf16* srcA1 = Ab + (size_t)(m0 + 128 + srow) * HFFN + schs * 8;
  const bf16* srcB0 = Bw + (size_t)(n0 + srow) * HFFN + schs * 8;
  const bf16* srcB1 = Bw + (size_t)(n0 + 128 + srow) * HFFN + schs * 8;
  if (routed && tid < 256) {
    s_tok[tid] = sel[e * CAP + m0 + tid];
    s_scl[tid] = scr[e * CAP + m0 + tid];
  }

  f32x4 acc[8][4];
  #pragma unroll
  for (int i = 0; i < 8; ++i)
    #pragma unroll
    for (int j = 0; j < 4; ++j) acc[i][j] = (f32x4){0.f, 0.f, 0.f, 0.f};

  const int fr = lane & 15;
  const int fch = ((lane >> 4) ^ (lane & 3)) * 8;
  const int NT = HFFN / 32;

  #define STAGE2(t, b) do { \
    bf16* As_ = smem + (b) * 16384; \
    const int ko = (t) * 32; \
    gload16(srcA0 + ko, As_ + ldst); \
    gload16(srcA1 + ko, As_ + 4096 + ldst); \
    gload16(srcB0 + ko, As_ + 8192 + ldst); \
    gload16(srcB1 + ko, As_ + 12288 + ldst); \
  } while (0)

  STAGE2(0, 0);
  STAGE2(1, 1);
  VMCNT(4);
  RAWBAR();

  int b = 0;
  for (int t = 0; t < NT; ++t) {
    int b2 = b + 2; if (b2 >= 3) b2 -= 3;
    if (t + 2 < NT) STAGE2(t + 2, b2);
    const bf16* As = smem + b * 16384;
    const bf16* Bs = As + 8192;
    bf16x8 av[8], bv[4];
    #pragma unroll
    for (int i = 0; i < 8; ++i)
      av[i] = *(const bf16x8*)(As + (wr * 128 + i * 16 + fr) * 32 + fch);
    #pragma unroll
    for (int j = 0; j < 4; ++j)
      bv[j] = *(const bf16x8*)(Bs + (wc * 64 + j * 16 + fr) * 32 + fch);
    __builtin_amdgcn_s_setprio(1);
    #pragma unroll
    for (int i = 0; i < 8; ++i)
      #pragma unroll
      for (int j = 0; j < 4; ++j)
        acc[i][j] = __builtin_amdgcn_mfma_f32_16x16x32_bf16(av[i], bv[j], acc[i][j], 0, 0, 0);
    __builtin_amdgcn_s_setprio(0);
    if (t + 2 < NT) { VMCNT(4); } else { VMCNT(0); }
    RAWBAR();
    if (++b == 3) b = 0;
  }
  #undef STAGE2

  if (!routed) {
    #pragma unroll
    for (int i = 0; i < 8; ++i) {
      #pragma unroll
      for (int j = 0; j < 4; ++j) {
        const int nl = wc * 64 + j * 16 + fr;
        const float bb = bias[n0 + nl];
        #pragma unroll
        for (int q = 0; q < 4; ++q) {
          const int ml = wr * 128 + i * 16 + (lane >> 4) * 4 + q;
          out[(size_t)(m0 + ml) * DMODEL + n0 + nl] = acc[i][j][q] + bb;
        }
      }
    }
  } else {
    __syncthreads();   // s_tok/s_scl visible (also ordered by loop barriers)
    #pragma unroll
    for (int i = 0; i < 8; ++i) {
      #pragma unroll
      for (int j = 0; j < 4; ++j) {
        const int nl = wc * 64 + j * 16 + fr;
        const float bb = bias[n0 + nl];
        #pragma unroll
        for (int q = 0; q < 4; ++q) {
          const int ml = wr * 128 + i * 16 + (lane >> 4) * 4 + q;
          const int tok = s_tok[ml];
          const float sc = s_scl[ml];
          atomicAdd(out + (size_t)tok * DMODEL + n0 + nl, (acc[i][j][q] + bb) * sc);
        }
      }
    }
  }
}

extern "C" void kernel_launch(void* const* d_in, const int* in_sizes, int n_in,
                              void* d_out, int out_size, void* d_ws, size_t ws_size,
                              hipStream_t stream) {
  const float* x   = (const float*)d_in[0];
  const float* gw  = (const float*)d_in[1];
  const float* ew1 = (const float*)d_in[2];
  const float* eb1 = (const float*)d_in[3];
  const float* ew2 = (const float*)d_in[4];
  const float* eb2 = (const float*)d_in[5];
  const float* sw1 = (const float*)d_in[6];
  const float* sb1 = (const float*)d_in[7];
  const float* sw2 = (const float*)d_in[8];
  const float* sb2 = (const float*)d_in[9];
  float* out = (float*)d_out;

  char* ws = (char*)d_ws;
  size_t off = 0;
  bf16* xb      = (bf16*)(ws + off); off += (size_t)NTOK * DMODEL * 2;
  bf16* w1t     = (bf16*)(ws + off); off += (size_t)9 * HFFN * DMODEL * 2;
  bf16* w2t     = (bf16*)(ws + off); off += (size_t)9 * DMODEL * HFFN * 2;
  bf16* hbuf    = (bf16*)(ws + off); off += (size_t)NTOK * HFFN * 2;
  float* probs  = (float*)(ws + off); off += (size_t)NEXP * NTOK * 4;
  int* selidx   = (int*)(ws + off);   off += (size_t)NEXP * CAP * 4;
  float* selscr = (float*)(ws + off); off += (size_t)NEXP * CAP * 4;

  cvt_x_kernel<<<dim3(NTOK * DMODEL / 8 / 256), dim3(256), 0, stream>>>(x, xb);
  router_kernel<<<dim3(NTOK), dim3(64), 0, stream>>>(x, gw, probs);
  topk_kernel<<<dim3(NEXP), dim3(256), 0, stream>>>(probs, selidx, selscr);
  transpose_cvt<<<dim3(HFFN / 64, DMODEL / 64, 9), dim3(256), 0, stream>>>(ew1, sw1, w1t, DMODEL, HFFN);
  transpose_cvt<<<dim3(DMODEL / 64, HFFN / 64, 9), dim3(256), 0, stream>>>(ew2, sw2, w2t, HFFN, DMODEL);

  ffn1_gemm<<<dim3(HFFN / 256, NTOK / 256, 1), dim3(512), 0, stream>>>(
      xb, w1t + (size_t)8 * HFFN * DMODEL, sb1, (const int*)nullptr, hbuf, 0);
  ffn2_gemm<<<dim3(DMODEL / 256, NTOK / 256, 1), dim3(512), 0, stream>>>(
      hbuf, w2t + (size_t)8 * DMODEL * HFFN, sb2, (const int*)nullptr, (const float*)nullptr, out, 0);

  ffn1_gemm<<<dim3(HFFN / 256, CAP / 256, NEXP), dim3(512), 0, stream>>>(
      xb, w1t, eb1, selidx, hbuf, 1);
  ffn2_gemm<<<dim3(DMODEL / 256, CAP / 256, NEXP), dim3(512), 0, stream>>>(
      hbuf, w2t, eb2, selidx, selscr, out, 1);
}

// Round 4
// 991.271 us; speedup vs baseline: 1.1856x; 1.0322x over previous
//
#include <hip/hip_runtime.h>

typedef __bf16 bf16;
typedef __bf16 bf16x8 __attribute__((ext_vector_type(8)));
typedef float f32x4 __attribute__((ext_vector_type(4)));

#define NTOK 16384
#define DMODEL 1024
#define HFFN 4096
#define NEXP 8
#define CAP 2048

#define VMCNT(n) asm volatile("s_waitcnt vmcnt(" #n ")" ::: "memory")
#define RAWBAR() do { __builtin_amdgcn_s_barrier(); __builtin_amdgcn_sched_barrier(0); } while (0)

__device__ __forceinline__ void gload16(const void* g, void* l) {
  __builtin_amdgcn_global_load_lds((const __attribute__((address_space(1))) void*)g,
                                   (__attribute__((address_space(3))) void*)l, 16, 0, 0);
}

__device__ __forceinline__ float gelu_f(float v) {
  float u = 0.7978845608028654f * (v + 0.044715f * v * v * v);
  float ex = __expf(2.0f * u);
  float th = 1.0f - 2.0f / (ex + 1.0f);
  return 0.5f * v * (1.0f + th);
}

// XCD-aware remap: all N-slots (bx) of one M-panel (by) land on one XCD,
// so the shared A-panel is served from that XCD's private L2.
// Bijective for gridDim.x a power of two and gridDim.y <= 8 or multiple of 8.
__device__ __forceinline__ void xcd_remap(int& bx, int& by) {
  const int gx = gridDim.x;
  const int lg = 31 - __clz((unsigned)gx);
  const int w = blockIdx.x + gx * blockIdx.y;
  bx = (w >> 3) & (gx - 1);
  by = (w & 7) | (((w >> 3) >> lg) << 3);
}

// ---------------- x: f32 -> bf16 ----------------
__global__ __launch_bounds__(256) void cvt_x_kernel(const float* __restrict__ x,
                                                    bf16* __restrict__ xb) {
  int i = blockIdx.x * blockDim.x + threadIdx.x;
  const float4* a = (const float4*)x + (size_t)i * 2;
  float4 v0 = a[0], v1 = a[1];
  bf16x8 o;
  o[0]=(bf16)v0.x; o[1]=(bf16)v0.y; o[2]=(bf16)v0.z; o[3]=(bf16)v0.w;
  o[4]=(bf16)v1.x; o[5]=(bf16)v1.y; o[6]=(bf16)v1.z; o[7]=(bf16)v1.w;
  *(bf16x8*)(xb + (size_t)i * 8) = o;
}

// ---------------- router ----------------
__global__ __launch_bounds__(64) void router_kernel(const float* __restrict__ x,
                                                    const float* __restrict__ gw,
                                                    float* __restrict__ probs) {
  int t = blockIdx.x;
  int l = threadIdx.x;
  int e = l & 7, chunk = l >> 3;
  const float* xr = x + (size_t)t * DMODEL + chunk * 128;
  const float* gwr = gw + (size_t)(chunk * 128) * NEXP + e;
  float a0 = 0.f, a1 = 0.f;
  #pragma unroll
  for (int d = 0; d < 128; d += 8) {
    float4 xv = *(const float4*)(xr + d);
    float4 xw = *(const float4*)(xr + d + 4);
    a0 += xv.x * gwr[(d+0)*8] + xv.y * gwr[(d+1)*8] + xv.z * gwr[(d+2)*8] + xv.w * gwr[(d+3)*8];
    a1 += xw.x * gwr[(d+4)*8] + xw.y * gwr[(d+5)*8] + xw.z * gwr[(d+6)*8] + xw.w * gwr[(d+7)*8];
  }
  float acc = a0 + a1;
  acc += __shfl_xor(acc, 8);
  acc += __shfl_xor(acc, 16);
  acc += __shfl_xor(acc, 32);
  float m = acc;
  m = fmaxf(m, __shfl_xor(m, 1));
  m = fmaxf(m, __shfl_xor(m, 2));
  m = fmaxf(m, __shfl_xor(m, 4));
  float ex = expf(acc - m);
  float s = ex;
  s += __shfl_xor(s, 1); s += __shfl_xor(s, 2); s += __shfl_xor(s, 4);
  if (l < 8) probs[(size_t)e * NTOK + t] = ex / s;
}

// ---------------- per-expert top-2048 radix select ----------------
__global__ __launch_bounds__(256) void topk_kernel(const float* __restrict__ probs,
                                                   int* __restrict__ oidx,
                                                   float* __restrict__ oscr) {
  const int e = blockIdx.x;
  const float* p = probs + (size_t)e * NTOK;
  const int t = threadIdx.x;
  __shared__ unsigned hist[256];
  __shared__ unsigned sg[256], sq[256];
  __shared__ unsigned bcast[4];
  unsigned pref = 0, krem = CAP;
  for (int pass = 0; pass < 4; ++pass) {
    const int sh = 24 - pass * 8;
    hist[t] = 0;
    __syncthreads();
    for (int j = 0; j < 64; ++j) {
      unsigned u = __float_as_uint(p[t * 64 + j]);
      bool ok = (pass == 0) || ((u >> (sh + 8)) == pref);
      if (ok) atomicAdd(&hist[(u >> sh) & 255u], 1u);
    }
    __syncthreads();
    if (t == 0) {
      unsigned cum = 0; int b = 255;
      for (; b > 0; --b) {
        unsigned c = hist[b];
        if (cum + c >= krem) break;
        cum += c;
      }
      bcast[0] = (pref << 8) | (unsigned)b;
      bcast[1] = krem - cum;
    }
    __syncthreads();
    pref = bcast[0];
    krem = bcast[1];
  }
  const unsigned thr = pref;
  const unsigned neq_take = krem;
  unsigned cgt = 0, ceq = 0;
  for (int j = 0; j < 64; ++j) {
    unsigned u = __float_as_uint(p[t * 64 + j]);
    cgt += (u > thr);
    ceq += (u == thr);
  }
  sg[t] = cgt; sq[t] = ceq;
  __syncthreads();
  if (t == 0) {
    unsigned ag = 0, aq = 0;
    for (int i = 0; i < 256; ++i) {
      unsigned g = sg[i], q = sq[i];
      sg[i] = ag; sq[i] = aq;
      ag += g; aq += q;
    }
    bcast[2] = ag;
  }
  __syncthreads();
  const unsigned ngt = bcast[2];
  unsigned og = sg[t], oq = sq[t];
  int* oi = oidx + e * CAP;
  float* os = oscr + e * CAP;
  for (int j = 0; j < 64; ++j) {
    int tok = t * 64 + j;
    float pv = p[tok];
    unsigned u = __float_as_uint(pv);
    if (u > thr) {
      oi[og] = tok; os[og] = pv; ++og;
    } else if (u == thr) {
      if (oq < neq_take) { oi[ngt + oq] = tok; os[ngt + oq] = pv; }
      ++oq;
    }
  }
}

// ---------------- weight transpose + cvt ----------------
__global__ __launch_bounds__(256) void transpose_cvt(const float* __restrict__ in_e,
                                                     const float* __restrict__ in_s,
                                                     bf16* __restrict__ outp,
                                                     int R, int C) {
  int z = blockIdx.z;
  const float* in = (z < 8) ? (in_e + (size_t)z * (size_t)R * C) : in_s;
  bf16* out = outp + (size_t)z * (size_t)R * C;
  __shared__ float tile[64][65];
  int tx = threadIdx.x & 63, ty = threadIdx.x >> 6;
  int c0 = blockIdx.x * 64, r0 = blockIdx.y * 64;
  #pragma unroll
  for (int j = 0; j < 16; ++j) {
    int r = ty + j * 4;
    tile[r][tx] = in[(size_t)(r0 + r) * C + c0 + tx];
  }
  __syncthreads();
  #pragma unroll
  for (int j = 0; j < 16; ++j) {
    int c = ty + j * 4;
    out[(size_t)(c0 + c) * R + r0 + tx] = (bf16)tile[tx][c];
  }
}

// =====================================================================
// 256x256 tile, BK=32, 512 threads, triple-buffered LDS ring, counted
// vmcnt. Swizzle key for a 64B row is (row>>1)&3: 16B-slot(r,c) =
// (4r + c) mod 8 -> slots cycle 0,4,1,5,2,6,3,7 => exact 2-way (free).
// =====================================================================

// ---------------- FFN up GEMM: h = gelu(A @ W1^T + b1) ----------------
__global__ __launch_bounds__(512, 2) void ffn1_gemm(const bf16* __restrict__ xb,
                                                    const bf16* __restrict__ w1t,
                                                    const float* __restrict__ bias1,
                                                    const int* __restrict__ sel,
                                                    bf16* __restrict__ hout,
                                                    int routed) {
  const int e = blockIdx.z;
  const bf16* Bw = w1t + (routed ? (size_t)e * HFFN * DMODEL : 0);
  const float* bias = bias1 + (routed ? (size_t)e * HFFN : 0);
  bf16* hb = hout + (routed ? (size_t)e * CAP * HFFN : 0);
  int bx, by;
  xcd_remap(bx, by);
  const int m0 = by * 256, n0 = bx * 256;
  __shared__ __align__(16) bf16 smem[49152];   // 96 KiB: 3 x (A 8192 | B 8192)
  const int tid = threadIdx.x, lane = tid & 63, wave = tid >> 6;
  const int wr = wave >> 2, wc = wave & 3;

  const int srow = tid >> 2, sch = tid & 3;
  const int schs = sch ^ ((srow >> 1) & 3);    // source-side swizzle
  const int ldst = srow * 32 + sch * 8;        // LDS dest (bf16), linear
  const bf16 *srcA0, *srcA1, *srcB0, *srcB1;
  {
    int r0i = routed ? sel[e * CAP + m0 + srow] : (m0 + srow);
    int r1i = routed ? sel[e * CAP + m0 + 128 + srow] : (m0 + 128 + srow);
    srcA0 = xb + (size_t)r0i * DMODEL + schs * 8;
    srcA1 = xb + (size_t)r1i * DMODEL + schs * 8;
    srcB0 = Bw + (size_t)(n0 + srow) * DMODEL + schs * 8;
    srcB1 = Bw + (size_t)(n0 + 128 + srow) * DMODEL + schs * 8;
  }

  f32x4 acc[8][4];
  #pragma unroll
  for (int i = 0; i < 8; ++i)
    #pragma unroll
    for (int j = 0; j < 4; ++j) acc[i][j] = (f32x4){0.f, 0.f, 0.f, 0.f};

  const int fr = lane & 15;
  const int fch = ((lane >> 4) ^ ((lane >> 1) & 3)) * 8;  // read-side swizzle
  const int NT = DMODEL / 32;

  #define STAGE1(t, b) do { \
    bf16* As_ = smem + (b) * 16384; \
    const int ko = (t) * 32; \
    gload16(srcA0 + ko, As_ + ldst); \
    gload16(srcA1 + ko, As_ + 4096 + ldst); \
    gload16(srcB0 + ko, As_ + 8192 + ldst); \
    gload16(srcB1 + ko, As_ + 12288 + ldst); \
  } while (0)

  STAGE1(0, 0);
  STAGE1(1, 1);
  VMCNT(4);
  RAWBAR();

  int b = 0;
  for (int t = 0; t < NT; ++t) {
    int b2 = b + 2; if (b2 >= 3) b2 -= 3;
    if (t + 2 < NT) STAGE1(t + 2, b2);
    const bf16* As = smem + b * 16384;
    const bf16* Bs = As + 8192;
    bf16x8 av[8], bv[4];
    #pragma unroll
    for (int i = 0; i < 8; ++i)
      av[i] = *(const bf16x8*)(As + (wr * 128 + i * 16 + fr) * 32 + fch);
    #pragma unroll
    for (int j = 0; j < 4; ++j)
      bv[j] = *(const bf16x8*)(Bs + (wc * 64 + j * 16 + fr) * 32 + fch);
    __builtin_amdgcn_s_setprio(1);
    #pragma unroll
    for (int i = 0; i < 8; ++i)
      #pragma unroll
      for (int j = 0; j < 4; ++j)
        acc[i][j] = __builtin_amdgcn_mfma_f32_16x16x32_bf16(av[i], bv[j], acc[i][j], 0, 0, 0);
    __builtin_amdgcn_s_setprio(0);
    if (t + 2 < NT) { VMCNT(4); } else { VMCNT(0); }
    RAWBAR();
    if (++b == 3) b = 0;
  }
  #undef STAGE1

  // epilogue: bias+gelu -> bf16, two 128-row halves through swizzled LDS bounce
  #pragma unroll
  for (int half = 0; half < 2; ++half) {
    if (wr == half) {
      #pragma unroll
      for (int i = 0; i < 8; ++i) {
        #pragma unroll
        for (int j = 0; j < 4; ++j) {
          const int nl = wc * 64 + j * 16 + fr;
          const float bb = bias[n0 + nl];
          #pragma unroll
          for (int q = 0; q < 4; ++q) {
            const int ml = i * 16 + (lane >> 4) * 4 + q;   // 0..127 in half
            smem[ml * 256 + (nl ^ (((ml >> 2) & 7) << 4))] =
                (bf16)gelu_f(acc[i][j][q] + bb);
          }
        }
      }
    }
    __syncthreads();
    #pragma unroll
    for (int p = 0; p < 8; ++p) {
      const int flat = p * 512 + tid;
      const int row = flat >> 5, nc8 = flat & 31;
      uint4 v = *(const uint4*)(smem + row * 256 + ((nc8 * 8) ^ (((row >> 2) & 7) << 4)));
      *(uint4*)(hb + (size_t)(m0 + half * 128 + row) * HFFN + n0 + nc8 * 8) = v;
    }
    __syncthreads();
  }
}

// ---------------- FFN down GEMM: y = h @ W2^T + b2 ----------------
__global__ __launch_bounds__(512, 2) void ffn2_gemm(const bf16* __restrict__ hbuf,
                                                    const bf16* __restrict__ w2t,
                                                    const float* __restrict__ bias2,
                                                    const int* __restrict__ sel,
                                                    const float* __restrict__ scr,
                                                    float* __restrict__ out,
                                                    int routed) {
  const int e = blockIdx.z;
  const bf16* Ab = hbuf + (routed ? (size_t)e * CAP * HFFN : 0);
  const bf16* Bw = w2t + (routed ? (size_t)e * DMODEL * HFFN : 0);
  const float* bias = bias2 + (routed ? (size_t)e * DMODEL : 0);
  int bx, by;
  xcd_remap(bx, by);
  const int m0 = by * 256, n0 = bx * 256;
  __shared__ __align__(16) bf16 smem[49152];
  __shared__ int s_tok[256];
  __shared__ float s_scl[256];
  const int tid = threadIdx.x, lane = tid & 63, wave = tid >> 6;
  const int wr = wave >> 2, wc = wave & 3;

  const int srow = tid >> 2, sch = tid & 3;
  const int schs = sch ^ ((srow >> 1) & 3);
  const int ldst = srow * 32 + sch * 8;
  const bf16* srcA0 = Ab + (size_t)(m0 + srow) * HFFN + schs * 8;
  const bf16* srcA1 = Ab + (size_t)(m0 + 128 + srow) * HFFN + schs * 8;
  const bf16* srcB0 = Bw + (size_t)(n0 + srow) * HFFN + schs * 8;
  const bf16* srcB1 = Bw + (size_t)(n0 + 128 + srow) * HFFN + schs * 8;
  if (routed && tid < 256) {
    s_tok[tid] = sel[e * CAP + m0 + tid];
    s_scl[tid] = scr[e * CAP + m0 + tid];
  }

  f32x4 acc[8][4];
  #pragma unroll
  for (int i = 0; i < 8; ++i)
    #pragma unroll
    for (int j = 0; j < 4; ++j) acc[i][j] = (f32x4){0.f, 0.f, 0.f, 0.f};

  const int fr = lane & 15;
  const int fch = ((lane >> 4) ^ ((lane >> 1) & 3)) * 8;
  const int NT = HFFN / 32;

  #define STAGE2(t, b) do { \
    bf16* As_ = smem + (b) * 16384; \
    const int ko = (t) * 32; \
    gload16(srcA0 + ko, As_ + ldst); \
    gload16(srcA1 + ko, As_ + 4096 + ldst); \
    gload16(srcB0 + ko, As_ + 8192 + ldst); \
    gload16(srcB1 + ko, As_ + 12288 + ldst); \
  } while (0)

  STAGE2(0, 0);
  STAGE2(1, 1);
  VMCNT(4);
  RAWBAR();

  int b = 0;
  for (int t = 0; t < NT; ++t) {
    int b2 = b + 2; if (b2 >= 3) b2 -= 3;
    if (t + 2 < NT) STAGE2(t + 2, b2);
    const bf16* As = smem + b * 16384;
    const bf16* Bs = As + 8192;
    bf16x8 av[8], bv[4];
    #pragma unroll
    for (int i = 0; i < 8; ++i)
      av[i] = *(const bf16x8*)(As + (wr * 128 + i * 16 + fr) * 32 + fch);
    #pragma unroll
    for (int j = 0; j < 4; ++j)
      bv[j] = *(const bf16x8*)(Bs + (wc * 64 + j * 16 + fr) * 32 + fch);
    __builtin_amdgcn_s_setprio(1);
    #pragma unroll
    for (int i = 0; i < 8; ++i)
      #pragma unroll
      for (int j = 0; j < 4; ++j)
        acc[i][j] = __builtin_amdgcn_mfma_f32_16x16x32_bf16(av[i], bv[j], acc[i][j], 0, 0, 0);
    __builtin_amdgcn_s_setprio(0);
    if (t + 2 < NT) { VMCNT(4); } else { VMCNT(0); }
    RAWBAR();
    if (++b == 3) b = 0;
  }
  #undef STAGE2

  if (!routed) {
    #pragma unroll
    for (int i = 0; i < 8; ++i) {
      #pragma unroll
      for (int j = 0; j < 4; ++j) {
        const int nl = wc * 64 + j * 16 + fr;
        const float bb = bias[n0 + nl];
        #pragma unroll
        for (int q = 0; q < 4; ++q) {
          const int ml = wr * 128 + i * 16 + (lane >> 4) * 4 + q;
          out[(size_t)(m0 + ml) * DMODEL + n0 + nl] = acc[i][j][q] + bb;
        }
      }
    }
  } else {
    __syncthreads();
    #pragma unroll
    for (int i = 0; i < 8; ++i) {
      #pragma unroll
      for (int j = 0; j < 4; ++j) {
        const int nl = wc * 64 + j * 16 + fr;
        const float bb = bias[n0 + nl];
        #pragma unroll
        for (int q = 0; q < 4; ++q) {
          const int ml = wr * 128 + i * 16 + (lane >> 4) * 4 + q;
          const int tok = s_tok[ml];
          const float sc = s_scl[ml];
          atomicAdd(out + (size_t)tok * DMODEL + n0 + nl, (acc[i][j][q] + bb) * sc);
        }
      }
    }
  }
}

extern "C" void kernel_launch(void* const* d_in, const int* in_sizes, int n_in,
                              void* d_out, int out_size, void* d_ws, size_t ws_size,
                              hipStream_t stream) {
  const float* x   = (const float*)d_in[0];
  const float* gw  = (const float*)d_in[1];
  const float* ew1 = (const float*)d_in[2];
  const float* eb1 = (const float*)d_in[3];
  const float* ew2 = (const float*)d_in[4];
  const float* eb2 = (const float*)d_in[5];
  const float* sw1 = (const float*)d_in[6];
  const float* sb1 = (const float*)d_in[7];
  const float* sw2 = (const float*)d_in[8];
  const float* sb2 = (const float*)d_in[9];
  float* out = (float*)d_out;

  char* ws = (char*)d_ws;
  size_t off = 0;
  bf16* xb      = (bf16*)(ws + off); off += (size_t)NTOK * DMODEL * 2;
  bf16* w1t     = (bf16*)(ws + off); off += (size_t)9 * HFFN * DMODEL * 2;
  bf16* w2t     = (bf16*)(ws + off); off += (size_t)9 * DMODEL * HFFN * 2;
  bf16* hbuf    = (bf16*)(ws + off); off += (size_t)NTOK * HFFN * 2;
  float* probs  = (float*)(ws + off); off += (size_t)NEXP * NTOK * 4;
  int* selidx   = (int*)(ws + off);   off += (size_t)NEXP * CAP * 4;
  float* selscr = (float*)(ws + off); off += (size_t)NEXP * CAP * 4;

  cvt_x_kernel<<<dim3(NTOK * DMODEL / 8 / 256), dim3(256), 0, stream>>>(x, xb);
  router_kernel<<<dim3(NTOK), dim3(64), 0, stream>>>(x, gw, probs);
  topk_kernel<<<dim3(NEXP), dim3(256), 0, stream>>>(probs, selidx, selscr);
  transpose_cvt<<<dim3(HFFN / 64, DMODEL / 64, 9), dim3(256), 0, stream>>>(ew1, sw1, w1t, DMODEL, HFFN);
  transpose_cvt<<<dim3(DMODEL / 64, HFFN / 64, 9), dim3(256), 0, stream>>>(ew2, sw2, w2t, HFFN, DMODEL);

  ffn1_gemm<<<dim3(HFFN / 256, NTOK / 256, 1), dim3(512), 0, stream>>>(
      xb, w1t + (size_t)8 * HFFN * DMODEL, sb1, (const int*)nullptr, hbuf, 0);
  ffn2_gemm<<<dim3(DMODEL / 256, NTOK / 256, 1), dim3(512), 0, stream>>>(
      hbuf, w2t + (size_t)8 * DMODEL * HFFN, sb2, (const int*)nullptr, (const float*)nullptr, out, 0);

  ffn1_gemm<<<dim3(HFFN / 256, CAP / 256, NEXP), dim3(512), 0, stream>>>(
      xb, w1t, eb1, selidx, hbuf, 1);
  ffn2_gemm<<<dim3(DMODEL / 256, CAP / 256, NEXP), dim3(512), 0, stream>>>(
      hbuf, w2t, eb2, selidx, selscr, out, 1);
}

// Round 5
// 976.771 us; speedup vs baseline: 1.2032x; 1.0148x over previous
//
#include <hip/hip_runtime.h>

typedef __bf16 bf16;
typedef __bf16 bf16x8 __attribute__((ext_vector_type(8)));
typedef float f32x4 __attribute__((ext_vector_type(4)));

#define NTOK 16384
#define DMODEL 1024
#define HFFN 4096
#define NEXP 8
#define CAP 2048

#define VMCNT(n) asm volatile("s_waitcnt vmcnt(" #n ")" ::: "memory")
#define LGKM0() do { asm volatile("s_waitcnt lgkmcnt(0)" ::: "memory"); \
                     __builtin_amdgcn_sched_barrier(0); } while (0)
#define RAWBAR() do { __builtin_amdgcn_sched_barrier(0); \
                      __builtin_amdgcn_s_barrier(); \
                      __builtin_amdgcn_sched_barrier(0); } while (0)

__device__ __forceinline__ void gload16(const void* g, void* l) {
  __builtin_amdgcn_global_load_lds((const __attribute__((address_space(1))) void*)g,
                                   (__attribute__((address_space(3))) void*)l, 16, 0, 0);
}

__device__ __forceinline__ float gelu_f(float v) {
  float u = 0.7978845608028654f * (v + 0.044715f * v * v * v);
  float ex = __expf(2.0f * u);
  float th = 1.0f - 2.0f / (ex + 1.0f);
  return 0.5f * v * (1.0f + th);
}

// XCD-aware remap: all N-slots (bx) of one M-panel (by) land on one XCD.
__device__ __forceinline__ void xcd_remap(int& bx, int& by) {
  const int gx = gridDim.x;
  const int lg = 31 - __clz((unsigned)gx);
  const int w = blockIdx.x + gx * blockIdx.y;
  bx = (w >> 3) & (gx - 1);
  by = (w & 7) | (((w >> 3) >> lg) << 3);
}

// ---------------- x: f32 -> bf16 ----------------
__global__ __launch_bounds__(256) void cvt_x_kernel(const float* __restrict__ x,
                                                    bf16* __restrict__ xb) {
  int i = blockIdx.x * blockDim.x + threadIdx.x;
  const float4* a = (const float4*)x + (size_t)i * 2;
  float4 v0 = a[0], v1 = a[1];
  bf16x8 o;
  o[0]=(bf16)v0.x; o[1]=(bf16)v0.y; o[2]=(bf16)v0.z; o[3]=(bf16)v0.w;
  o[4]=(bf16)v1.x; o[5]=(bf16)v1.y; o[6]=(bf16)v1.z; o[7]=(bf16)v1.w;
  *(bf16x8*)(xb + (size_t)i * 8) = o;
}

// ---------------- router ----------------
__global__ __launch_bounds__(64) void router_kernel(const float* __restrict__ x,
                                                    const float* __restrict__ gw,
                                                    float* __restrict__ probs) {
  int t = blockIdx.x;
  int l = threadIdx.x;
  int e = l & 7, chunk = l >> 3;
  const float* xr = x + (size_t)t * DMODEL + chunk * 128;
  const float* gwr = gw + (size_t)(chunk * 128) * NEXP + e;
  float a0 = 0.f, a1 = 0.f;
  #pragma unroll
  for (int d = 0; d < 128; d += 8) {
    float4 xv = *(const float4*)(xr + d);
    float4 xw = *(const float4*)(xr + d + 4);
    a0 += xv.x * gwr[(d+0)*8] + xv.y * gwr[(d+1)*8] + xv.z * gwr[(d+2)*8] + xv.w * gwr[(d+3)*8];
    a1 += xw.x * gwr[(d+4)*8] + xw.y * gwr[(d+5)*8] + xw.z * gwr[(d+6)*8] + xw.w * gwr[(d+7)*8];
  }
  float acc = a0 + a1;
  acc += __shfl_xor(acc, 8);
  acc += __shfl_xor(acc, 16);
  acc += __shfl_xor(acc, 32);
  float m = acc;
  m = fmaxf(m, __shfl_xor(m, 1));
  m = fmaxf(m, __shfl_xor(m, 2));
  m = fmaxf(m, __shfl_xor(m, 4));
  float ex = expf(acc - m);
  float s = ex;
  s += __shfl_xor(s, 1); s += __shfl_xor(s, 2); s += __shfl_xor(s, 4);
  if (l < 8) probs[(size_t)e * NTOK + t] = ex / s;
}

// ---------------- per-expert top-2048 radix select ----------------
__global__ __launch_bounds__(256) void topk_kernel(const float* __restrict__ probs,
                                                   int* __restrict__ oidx,
                                                   float* __restrict__ oscr) {
  const int e = blockIdx.x;
  const float* p = probs + (size_t)e * NTOK;
  const int t = threadIdx.x;
  __shared__ unsigned hist[256];
  __shared__ unsigned sg[256], sq[256];
  __shared__ unsigned bcast[4];
  unsigned pref = 0, krem = CAP;
  for (int pass = 0; pass < 4; ++pass) {
    const int sh = 24 - pass * 8;
    hist[t] = 0;
    __syncthreads();
    for (int j = 0; j < 64; ++j) {
      unsigned u = __float_as_uint(p[t * 64 + j]);
      bool ok = (pass == 0) || ((u >> (sh + 8)) == pref);
      if (ok) atomicAdd(&hist[(u >> sh) & 255u], 1u);
    }
    __syncthreads();
    if (t == 0) {
      unsigned cum = 0; int b = 255;
      for (; b > 0; --b) {
        unsigned c = hist[b];
        if (cum + c >= krem) break;
        cum += c;
      }
      bcast[0] = (pref << 8) | (unsigned)b;
      bcast[1] = krem - cum;
    }
    __syncthreads();
    pref = bcast[0];
    krem = bcast[1];
  }
  const unsigned thr = pref;
  const unsigned neq_take = krem;
  unsigned cgt = 0, ceq = 0;
  for (int j = 0; j < 64; ++j) {
    unsigned u = __float_as_uint(p[t * 64 + j]);
    cgt += (u > thr);
    ceq += (u == thr);
  }
  sg[t] = cgt; sq[t] = ceq;
  __syncthreads();
  if (t == 0) {
    unsigned ag = 0, aq = 0;
    for (int i = 0; i < 256; ++i) {
      unsigned g = sg[i], q = sq[i];
      sg[i] = ag; sq[i] = aq;
      ag += g; aq += q;
    }
    bcast[2] = ag;
  }
  __syncthreads();
  const unsigned ngt = bcast[2];
  unsigned og = sg[t], oq = sq[t];
  int* oi = oidx + e * CAP;
  float* os = oscr + e * CAP;
  for (int j = 0; j < 64; ++j) {
    int tok = t * 64 + j;
    float pv = p[tok];
    unsigned u = __float_as_uint(pv);
    if (u > thr) {
      oi[og] = tok; os[og] = pv; ++og;
    } else if (u == thr) {
      if (oq < neq_take) { oi[ngt + oq] = tok; os[ngt + oq] = pv; }
      ++oq;
    }
  }
}

// ---------------- weight transpose + cvt ----------------
__global__ __launch_bounds__(256) void transpose_cvt(const float* __restrict__ in_e,
                                                     const float* __restrict__ in_s,
                                                     bf16* __restrict__ outp,
                                                     int R, int C) {
  int z = blockIdx.z;
  const float* in = (z < 8) ? (in_e + (size_t)z * (size_t)R * C) : in_s;
  bf16* out = outp + (size_t)z * (size_t)R * C;
  __shared__ float tile[64][65];
  int tx = threadIdx.x & 63, ty = threadIdx.x >> 6;
  int c0 = blockIdx.x * 64, r0 = blockIdx.y * 64;
  #pragma unroll
  for (int j = 0; j < 16; ++j) {
    int r = ty + j * 4;
    tile[r][tx] = in[(size_t)(r0 + r) * C + c0 + tx];
  }
  __syncthreads();
  #pragma unroll
  for (int j = 0; j < 16; ++j) {
    int c = ty + j * 4;
    out[(size_t)(c0 + c) * R + r0 + tx] = (bf16)tile[tx][c];
  }
}

// =====================================================================
// 256x256 tile, BK=32, 512 threads, 3-buffer LDS ring, counted vmcnt,
// 4 fine phases per K-step: {ds_read subtile | stage 1 half-tile |
// barrier | lgkm0 | 8 MFMA | barrier}. Stage of tile t+2 never targets
// the buffer being read (ring distance 2 mod 3) -> race-free.
// =====================================================================

#define STAGE(t, bb) do { \
  bf16* S_ = smem + (bb) * 16384; \
  const int ko_ = (t) * 32; \
  gload16(srcA0 + ko_, S_ + ldst); \
  gload16(srcA1 + ko_, S_ + 4096 + ldst); \
  gload16(srcB0 + ko_, S_ + 8192 + ldst); \
  gload16(srcB1 + ko_, S_ + 12288 + ldst); \
} while (0)

#define MFMA_BLK(ILO, JLO) \
  _Pragma("unroll") \
  for (int i = 0; i < 4; ++i) \
    _Pragma("unroll") \
    for (int j = 0; j < 2; ++j) \
      acc[(ILO) + i][(JLO) + j] = __builtin_amdgcn_mfma_f32_16x16x32_bf16( \
          (ILO) ? avh[i] : avl[i], bv[(JLO) + j], acc[(ILO) + i][(JLO) + j], 0, 0, 0)

#define KLOOP(NT) do { \
  STAGE(0, 0); \
  STAGE(1, 1); \
  VMCNT(4); \
  RAWBAR(); \
  int b = 0; \
  for (int t = 0; t < (NT); ++t) { \
    int b2 = b + 2; if (b2 >= 3) b2 -= 3; \
    const bool st = (t + 2 < (NT)); \
    bf16* S2 = smem + b2 * 16384; \
    const int ko2 = (t + 2) * 32; \
    const bf16* As = smem + b * 16384; \
    const bf16* Bs = As + 8192; \
    bf16x8 avl[4], avh[4], bv[4]; \
    /* ---- P0: avl + bv01 | stage A-lo | MFMA q(0,0) ---- */ \
    _Pragma("unroll") \
    for (int i = 0; i < 4; ++i) \
      avl[i] = *(const bf16x8*)(As + (wr * 128 + i * 16 + fr) * 32 + fch); \
    bv[0] = *(const bf16x8*)(Bs + (wc * 64 + fr) * 32 + fch); \
    bv[1] = *(const bf16x8*)(Bs + (wc * 64 + 16 + fr) * 32 + fch); \
    if (st) gload16(srcA0 + ko2, S2 + ldst); \
    RAWBAR(); LGKM0(); \
    __builtin_amdgcn_s_setprio(1); MFMA_BLK(0, 0); __builtin_amdgcn_s_setprio(0); \
    RAWBAR(); \
    /* ---- P1: bv23 | stage A-hi | MFMA q(0,1) ---- */ \
    bv[2] = *(const bf16x8*)(Bs + (wc * 64 + 32 + fr) * 32 + fch); \
    bv[3] = *(const bf16x8*)(Bs + (wc * 64 + 48 + fr) * 32 + fch); \
    if (st) gload16(srcA1 + ko2, S2 + 4096 + ldst); \
    RAWBAR(); LGKM0(); \
    __builtin_amdgcn_s_setprio(1); MFMA_BLK(0, 2); __builtin_amdgcn_s_setprio(0); \
    RAWBAR(); \
    /* ---- P2: avh | stage B-lo | MFMA q(1,0) ---- */ \
    _Pragma("unroll") \
    for (int i = 0; i < 4; ++i) \
      avh[i] = *(const bf16x8*)(As + (wr * 128 + 64 + i * 16 + fr) * 32 + fch); \
    if (st) gload16(srcB0 + ko2, S2 + 8192 + ldst); \
    RAWBAR(); LGKM0(); \
    __builtin_amdgcn_s_setprio(1); MFMA_BLK(4, 0); __builtin_amdgcn_s_setprio(0); \
    RAWBAR(); \
    /* ---- P3: stage B-hi | MFMA q(1,1) | vmcnt gate ---- */ \
    if (st) gload16(srcB1 + ko2, S2 + 12288 + ldst); \
    __builtin_amdgcn_s_setprio(1); MFMA_BLK(4, 2); __builtin_amdgcn_s_setprio(0); \
    if (st) { VMCNT(4); } else { VMCNT(0); } \
    RAWBAR(); \
    if (++b == 3) b = 0; \
  } \
} while (0)

// ---------------- FFN up GEMM: h = gelu(A @ W1^T + b1) ----------------
__global__ __launch_bounds__(512, 2) void ffn1_gemm(const bf16* __restrict__ xb,
                                                    const bf16* __restrict__ w1t,
                                                    const float* __restrict__ bias1,
                                                    const int* __restrict__ sel,
                                                    bf16* __restrict__ hout,
                                                    int routed) {
  const int e = blockIdx.z;
  const bf16* Bw = w1t + (routed ? (size_t)e * HFFN * DMODEL : 0);
  const float* bias = bias1 + (routed ? (size_t)e * HFFN : 0);
  bf16* hb = hout + (routed ? (size_t)e * CAP * HFFN : 0);
  int bx, by;
  xcd_remap(bx, by);
  const int m0 = by * 256, n0 = bx * 256;
  __shared__ __align__(16) bf16 smem[49152];   // 96 KiB: 3 x (A 8192 | B 8192)
  const int tid = threadIdx.x, lane = tid & 63, wave = tid >> 6;
  const int wr = wave >> 2, wc = wave & 3;

  const int srow = tid >> 2, sch = tid & 3;
  const int schs = sch ^ ((srow >> 1) & 3);    // source-side swizzle
  const int ldst = srow * 32 + sch * 8;        // LDS dest (bf16), linear
  const bf16 *srcA0, *srcA1, *srcB0, *srcB1;
  {
    int r0i = routed ? sel[e * CAP + m0 + srow] : (m0 + srow);
    int r1i = routed ? sel[e * CAP + m0 + 128 + srow] : (m0 + 128 + srow);
    srcA0 = xb + (size_t)r0i * DMODEL + schs * 8;
    srcA1 = xb + (size_t)r1i * DMODEL + schs * 8;
    srcB0 = Bw + (size_t)(n0 + srow) * DMODEL + schs * 8;
    srcB1 = Bw + (size_t)(n0 + 128 + srow) * DMODEL + schs * 8;
  }

  f32x4 acc[8][4];
  #pragma unroll
  for (int i = 0; i < 8; ++i)
    #pragma unroll
    for (int j = 0; j < 4; ++j) acc[i][j] = (f32x4){0.f, 0.f, 0.f, 0.f};

  const int fr = lane & 15;
  const int fch = ((lane >> 4) ^ ((lane >> 1) & 3)) * 8;  // read-side swizzle

  KLOOP(DMODEL / 32);

  // epilogue: bias+gelu -> bf16, two 128-row halves through swizzled LDS bounce
  #pragma unroll
  for (int half = 0; half < 2; ++half) {
    if (wr == half) {
      #pragma unroll
      for (int i = 0; i < 8; ++i) {
        #pragma unroll
        for (int j = 0; j < 4; ++j) {
          const int nl = wc * 64 + j * 16 + fr;
          const float bb = bias[n0 + nl];
          #pragma unroll
          for (int q = 0; q < 4; ++q) {
            const int ml = i * 16 + (lane >> 4) * 4 + q;   // 0..127 in half
            smem[ml * 256 + (nl ^ (((ml >> 2) & 7) << 4))] =
                (bf16)gelu_f(acc[i][j][q] + bb);
          }
        }
      }
    }
    __syncthreads();
    #pragma unroll
    for (int p = 0; p < 8; ++p) {
      const int flat = p * 512 + tid;
      const int row = flat >> 5, nc8 = flat & 31;
      uint4 v = *(const uint4*)(smem + row * 256 + ((nc8 * 8) ^ (((row >> 2) & 7) << 4)));
      *(uint4*)(hb + (size_t)(m0 + half * 128 + row) * HFFN + n0 + nc8 * 8) = v;
    }
    __syncthreads();
  }
}

// ---------------- FFN down GEMM: y = h @ W2^T + b2 ----------------
__global__ __launch_bounds__(512, 2) void ffn2_gemm(const bf16* __restrict__ hbuf,
                                                    const bf16* __restrict__ w2t,
                                                    const float* __restrict__ bias2,
                                                    const int* __restrict__ sel,
                                                    const float* __restrict__ scr,
                                                    float* __restrict__ out,
                                                    int routed) {
  const int e = blockIdx.z;
  const bf16* Ab = hbuf + (routed ? (size_t)e * CAP * HFFN : 0);
  const bf16* Bw = w2t + (routed ? (size_t)e * DMODEL * HFFN : 0);
  const float* bias = bias2 + (routed ? (size_t)e * DMODEL : 0);
  int bx, by;
  xcd_remap(bx, by);
  const int m0 = by * 256, n0 = bx * 256;
  __shared__ __align__(16) bf16 smem[49152];
  __shared__ int s_tok[256];
  __shared__ float s_scl[256];
  const int tid = threadIdx.x, lane = tid & 63, wave = tid >> 6;
  const int wr = wave >> 2, wc = wave & 3;

  const int srow = tid >> 2, sch = tid & 3;
  const int schs = sch ^ ((srow >> 1) & 3);
  const int ldst = srow * 32 + sch * 8;
  const bf16* srcA0 = Ab + (size_t)(m0 + srow) * HFFN + schs * 8;
  const bf16* srcA1 = Ab + (size_t)(m0 + 128 + srow) * HFFN + schs * 8;
  const bf16* srcB0 = Bw + (size_t)(n0 + srow) * HFFN + schs * 8;
  const bf16* srcB1 = Bw + (size_t)(n0 + 128 + srow) * HFFN + schs * 8;
  if (routed && tid < 256) {
    s_tok[tid] = sel[e * CAP + m0 + tid];
    s_scl[tid] = scr[e * CAP + m0 + tid];
  }

  f32x4 acc[8][4];
  #pragma unroll
  for (int i = 0; i < 8; ++i)
    #pragma unroll
    for (int j = 0; j < 4; ++j) acc[i][j] = (f32x4){0.f, 0.f, 0.f, 0.f};

  const int fr = lane & 15;
  const int fch = ((lane >> 4) ^ ((lane >> 1) & 3)) * 8;

  KLOOP(HFFN / 32);

  if (!routed) {
    #pragma unroll
    for (int i = 0; i < 8; ++i) {
      #pragma unroll
      for (int j = 0; j < 4; ++j) {
        const int nl = wc * 64 + j * 16 + fr;
        const float bb = bias[n0 + nl];
        #pragma unroll
        for (int q = 0; q < 4; ++q) {
          const int ml = wr * 128 + i * 16 + (lane >> 4) * 4 + q;
          out[(size_t)(m0 + ml) * DMODEL + n0 + nl] = acc[i][j][q] + bb;
        }
      }
    }
  } else {
    __syncthreads();
    #pragma unroll
    for (int i = 0; i < 8; ++i) {
      #pragma unroll
      for (int j = 0; j < 4; ++j) {
        const int nl = wc * 64 + j * 16 + fr;
        const float bb = bias[n0 + nl];
        #pragma unroll
        for (int q = 0; q < 4; ++q) {
          const int ml = wr * 128 + i * 16 + (lane >> 4) * 4 + q;
          const int tok = s_tok[ml];
          const float sc = s_scl[ml];
          atomicAdd(out + (size_t)tok * DMODEL + n0 + nl, (acc[i][j][q] + bb) * sc);
        }
      }
    }
  }
}

extern "C" void kernel_launch(void* const* d_in, const int* in_sizes, int n_in,
                              void* d_out, int out_size, void* d_ws, size_t ws_size,
                              hipStream_t stream) {
  const float* x   = (const float*)d_in[0];
  const float* gw  = (const float*)d_in[1];
  const float* ew1 = (const float*)d_in[2];
  const float* eb1 = (const float*)d_in[3];
  const float* ew2 = (const float*)d_in[4];
  const float* eb2 = (const float*)d_in[5];
  const float* sw1 = (const float*)d_in[6];
  const float* sb1 = (const float*)d_in[7];
  const float* sw2 = (const float*)d_in[8];
  const float* sb2 = (const float*)d_in[9];
  float* out = (float*)d_out;

  char* ws = (char*)d_ws;
  size_t off = 0;
  bf16* xb      = (bf16*)(ws + off); off += (size_t)NTOK * DMODEL * 2;
  bf16* w1t     = (bf16*)(ws + off); off += (size_t)9 * HFFN * DMODEL * 2;
  bf16* w2t     = (bf16*)(ws + off); off += (size_t)9 * DMODEL * HFFN * 2;
  bf16* hbuf    = (bf16*)(ws + off); off += (size_t)NTOK * HFFN * 2;
  float* probs  = (float*)(ws + off); off += (size_t)NEXP * NTOK * 4;
  int* selidx   = (int*)(ws + off);   off += (size_t)NEXP * CAP * 4;
  float* selscr = (float*)(ws + off); off += (size_t)NEXP * CAP * 4;

  cvt_x_kernel<<<dim3(NTOK * DMODEL / 8 / 256), dim3(256), 0, stream>>>(x, xb);
  router_kernel<<<dim3(NTOK), dim3(64), 0, stream>>>(x, gw, probs);
  topk_kernel<<<dim3(NEXP), dim3(256), 0, stream>>>(probs, selidx, selscr);
  transpose_cvt<<<dim3(HFFN / 64, DMODEL / 64, 9), dim3(256), 0, stream>>>(ew1, sw1, w1t, DMODEL, HFFN);
  transpose_cvt<<<dim3(DMODEL / 64, HFFN / 64, 9), dim3(256), 0, stream>>>(ew2, sw2, w2t, HFFN, DMODEL);

  ffn1_gemm<<<dim3(HFFN / 256, NTOK / 256, 1), dim3(512), 0, stream>>>(
      xb, w1t + (size_t)8 * HFFN * DMODEL, sb1, (const int*)nullptr, hbuf, 0);
  ffn2_gemm<<<dim3(DMODEL / 256, NTOK / 256, 1), dim3(512), 0, stream>>>(
      hbuf, w2t + (size_t)8 * DMODEL * HFFN, sb2, (const int*)nullptr, (const float*)nullptr, out, 0);

  ffn1_gemm<<<dim3(HFFN / 256, CAP / 256, NEXP), dim3(512), 0, stream>>>(
      xb, w1t, eb1, selidx, hbuf, 1);
  ffn2_gemm<<<dim3(DMODEL / 256, CAP / 256, NEXP), dim3(512), 0, stream>>>(
      hbuf, w2t, eb2, selidx, selscr, out, 1);
}

// Round 6
// 897.230 us; speedup vs baseline: 1.3099x; 1.0887x over previous
//
#include <hip/hip_runtime.h>

typedef __bf16 bf16;
typedef __bf16 bf16x8 __attribute__((ext_vector_type(8)));
typedef float f32x4 __attribute__((ext_vector_type(4)));

#define NTOK 16384
#define DMODEL 1024
#define HFFN 4096
#define NEXP 8
#define CAP 2048

#define VMCNT(n) asm volatile("s_waitcnt vmcnt(" #n ")" ::: "memory")
#define LGKM0() do { asm volatile("s_waitcnt lgkmcnt(0)" ::: "memory"); \
                     __builtin_amdgcn_sched_barrier(0); } while (0)
#define RAWBAR() do { __builtin_amdgcn_sched_barrier(0); \
                      __builtin_amdgcn_s_barrier(); \
                      __builtin_amdgcn_sched_barrier(0); } while (0)

__device__ __forceinline__ void gload16(const void* g, void* l) {
  __builtin_amdgcn_global_load_lds((const __attribute__((address_space(1))) void*)g,
                                   (__attribute__((address_space(3))) void*)l, 16, 0, 0);
}

__device__ __forceinline__ float gelu_f(float v) {
  float u = 0.7978845608028654f * (v + 0.044715f * v * v * v);
  float ex = __expf(2.0f * u);
  float th = 1.0f - 2.0f / (ex + 1.0f);
  return 0.5f * v * (1.0f + th);
}

// XCD-aware remap: all N-slots (bx) of one M-panel (by) land on one XCD.
__device__ __forceinline__ void xcd_remap(int& bx, int& by) {
  const int gx = gridDim.x;
  const int lg = 31 - __clz((unsigned)gx);
  const int w = blockIdx.x + gx * blockIdx.y;
  bx = (w >> 3) & (gx - 1);
  by = (w & 7) | (((w >> 3) >> lg) << 3);
}

// ---------------- x: f32 -> bf16 ----------------
__global__ __launch_bounds__(256) void cvt_x_kernel(const float* __restrict__ x,
                                                    bf16* __restrict__ xb) {
  int i = blockIdx.x * blockDim.x + threadIdx.x;
  const float4* a = (const float4*)x + (size_t)i * 2;
  float4 v0 = a[0], v1 = a[1];
  bf16x8 o;
  o[0]=(bf16)v0.x; o[1]=(bf16)v0.y; o[2]=(bf16)v0.z; o[3]=(bf16)v0.w;
  o[4]=(bf16)v1.x; o[5]=(bf16)v1.y; o[6]=(bf16)v1.z; o[7]=(bf16)v1.w;
  *(bf16x8*)(xb + (size_t)i * 8) = o;
}

// ---------------- router ----------------
__global__ __launch_bounds__(64) void router_kernel(const float* __restrict__ x,
                                                    const float* __restrict__ gw,
                                                    float* __restrict__ probs) {
  int t = blockIdx.x;
  int l = threadIdx.x;
  int e = l & 7, chunk = l >> 3;
  const float* xr = x + (size_t)t * DMODEL + chunk * 128;
  const float* gwr = gw + (size_t)(chunk * 128) * NEXP + e;
  float a0 = 0.f, a1 = 0.f;
  #pragma unroll
  for (int d = 0; d < 128; d += 8) {
    float4 xv = *(const float4*)(xr + d);
    float4 xw = *(const float4*)(xr + d + 4);
    a0 += xv.x * gwr[(d+0)*8] + xv.y * gwr[(d+1)*8] + xv.z * gwr[(d+2)*8] + xv.w * gwr[(d+3)*8];
    a1 += xw.x * gwr[(d+4)*8] + xw.y * gwr[(d+5)*8] + xw.z * gwr[(d+6)*8] + xw.w * gwr[(d+7)*8];
  }
  float acc = a0 + a1;
  acc += __shfl_xor(acc, 8);
  acc += __shfl_xor(acc, 16);
  acc += __shfl_xor(acc, 32);
  float m = acc;
  m = fmaxf(m, __shfl_xor(m, 1));
  m = fmaxf(m, __shfl_xor(m, 2));
  m = fmaxf(m, __shfl_xor(m, 4));
  float ex = expf(acc - m);
  float s = ex;
  s += __shfl_xor(s, 1); s += __shfl_xor(s, 2); s += __shfl_xor(s, 4);
  if (l < 8) probs[(size_t)e * NTOK + t] = ex / s;
}

// ---------------- per-expert top-2048 radix select ----------------
__global__ __launch_bounds__(256) void topk_kernel(const float* __restrict__ probs,
                                                   int* __restrict__ oidx,
                                                   float* __restrict__ oscr) {
  const int e = blockIdx.x;
  const float* p = probs + (size_t)e * NTOK;
  const int t = threadIdx.x;
  __shared__ unsigned hist[256];
  __shared__ unsigned sg[256], sq[256];
  __shared__ unsigned bcast[4];
  unsigned pref = 0, krem = CAP;
  for (int pass = 0; pass < 4; ++pass) {
    const int sh = 24 - pass * 8;
    hist[t] = 0;
    __syncthreads();
    for (int j = 0; j < 64; ++j) {
      unsigned u = __float_as_uint(p[t * 64 + j]);
      bool ok = (pass == 0) || ((u >> (sh + 8)) == pref);
      if (ok) atomicAdd(&hist[(u >> sh) & 255u], 1u);
    }
    __syncthreads();
    if (t == 0) {
      unsigned cum = 0; int b = 255;
      for (; b > 0; --b) {
        unsigned c = hist[b];
        if (cum + c >= krem) break;
        cum += c;
      }
      bcast[0] = (pref << 8) | (unsigned)b;
      bcast[1] = krem - cum;
    }
    __syncthreads();
    pref = bcast[0];
    krem = bcast[1];
  }
  const unsigned thr = pref;
  const unsigned neq_take = krem;
  unsigned cgt = 0, ceq = 0;
  for (int j = 0; j < 64; ++j) {
    unsigned u = __float_as_uint(p[t * 64 + j]);
    cgt += (u > thr);
    ceq += (u == thr);
  }
  sg[t] = cgt; sq[t] = ceq;
  __syncthreads();
  if (t == 0) {
    unsigned ag = 0, aq = 0;
    for (int i = 0; i < 256; ++i) {
      unsigned g = sg[i], q = sq[i];
      sg[i] = ag; sq[i] = aq;
      ag += g; aq += q;
    }
    bcast[2] = ag;
  }
  __syncthreads();
  const unsigned ngt = bcast[2];
  unsigned og = sg[t], oq = sq[t];
  int* oi = oidx + e * CAP;
  float* os = oscr + e * CAP;
  for (int j = 0; j < 64; ++j) {
    int tok = t * 64 + j;
    float pv = p[tok];
    unsigned u = __float_as_uint(pv);
    if (u > thr) {
      oi[og] = tok; os[og] = pv; ++og;
    } else if (u == thr) {
      if (oq < neq_take) { oi[ngt + oq] = tok; os[ngt + oq] = pv; }
      ++oq;
    }
  }
}

// ---------------- weight transpose + cvt ----------------
__global__ __launch_bounds__(256) void transpose_cvt(const float* __restrict__ in_e,
                                                     const float* __restrict__ in_s,
                                                     bf16* __restrict__ outp,
                                                     int R, int C) {
  int z = blockIdx.z;
  const float* in = (z < 8) ? (in_e + (size_t)z * (size_t)R * C) : in_s;
  bf16* out = outp + (size_t)z * (size_t)R * C;
  __shared__ float tile[64][65];
  int tx = threadIdx.x & 63, ty = threadIdx.x >> 6;
  int c0 = blockIdx.x * 64, r0 = blockIdx.y * 64;
  #pragma unroll
  for (int j = 0; j < 16; ++j) {
    int r = ty + j * 4;
    tile[r][tx] = in[(size_t)(r0 + r) * C + c0 + tx];
  }
  __syncthreads();
  #pragma unroll
  for (int j = 0; j < 16; ++j) {
    int c = ty + j * 4;
    out[(size_t)(c0 + c) * R + r0 + tx] = (bf16)tile[tx][c];
  }
}

// =====================================================================
// m201-style 8-phase schedule: 256x256 tile, BK=64, 512 threads, 2 LDS
// buffers (A 256x64 | B 256x64 each = 64KB; 2 bufs = 128KB). Tile t in
// buf t&1; tile t+2 staged INTO the buffer being read, at phases where
// its region is provably free: A-mh0 slabs free after ph0 -> staged ph1;
// B slabs free after ph1 (frags held in regs for ph2/ph3) -> staged ph2;
// A-mh1 free after ph2 -> staged ph3. Gate vmcnt(8) once per K-tile
// (the 8 newest per-wave loads = its own t+2 stages) -> each load gets
// ~4 phases of latency cover; never drains in steady state.
// Swizzle: LDS(row, c16) holds global chunk c ^ (row&7); read-side same.
// =====================================================================

#define STAGE_TILE_ALL(tt) do { \
  bf16* D_ = smem + (((tt) & 1) << 15); \
  const int ko_ = (tt) * 64; \
  gload16(srcA0 + ko_, D_ + tid8); \
  gload16(srcA1 + ko_, D_ + 4096 + tid8); \
  gload16(srcA2 + ko_, D_ + 8192 + tid8); \
  gload16(srcA3 + ko_, D_ + 12288 + tid8); \
  gload16(srcB0 + ko_, D_ + 16384 + tid8); \
  gload16(srcB1 + ko_, D_ + 20480 + tid8); \
  gload16(srcB2 + ko_, D_ + 24576 + tid8); \
  gload16(srcB3 + ko_, D_ + 28672 + tid8); \
} while (0)

#define KLOOP8(NT) do { \
  STAGE_TILE_ALL(0); \
  STAGE_TILE_ALL(1); \
  VMCNT(8); \
  RAWBAR(); \
  for (int t = 0; t < (NT); ++t) { \
    const bf16* Ab_ = smem + ((t & 1) << 15); \
    const bf16* Bb_ = Ab_ + 16384; \
    bf16* Sn_ = smem + ((t & 1) << 15); \
    const int ko2 = (t + 2) * 64; \
    const bool st = (t + 2) < (NT); \
    bf16x8 aA[8], aB[8]; \
    /* ---- ph0: read A-mh0 (8) + B-nh0 (4); MFMA quad (0,0) ---- */ \
    _Pragma("unroll") for (int i = 0; i < 4; ++i) { \
      aA[i*2+0] = *(const bf16x8*)(Ab_ + (wr*128 + i*16 + fr)*64 + c0s); \
      aA[i*2+1] = *(const bf16x8*)(Ab_ + (wr*128 + i*16 + fr)*64 + c1s); \
    } \
    _Pragma("unroll") for (int j = 0; j < 2; ++j) { \
      aB[j*2+0] = *(const bf16x8*)(Bb_ + (wc*64 + j*16 + fr)*64 + c0s); \
      aB[j*2+1] = *(const bf16x8*)(Bb_ + (wc*64 + j*16 + fr)*64 + c1s); \
    } \
    RAWBAR(); LGKM0(); \
    __builtin_amdgcn_s_setprio(1); \
    _Pragma("unroll") for (int i = 0; i < 4; ++i) \
      _Pragma("unroll") for (int j = 0; j < 2; ++j) { \
        acc[i][j] = __builtin_amdgcn_mfma_f32_16x16x32_bf16(aA[i*2+0], aB[j*2+0], acc[i][j], 0, 0, 0); \
        acc[i][j] = __builtin_amdgcn_mfma_f32_16x16x32_bf16(aA[i*2+1], aB[j*2+1], acc[i][j], 0, 0, 0); \
      } \
    __builtin_amdgcn_s_setprio(0); \
    RAWBAR(); \
    /* ---- ph1: read B-nh1 (4); stage A02(t+2); MFMA quad (0,1) ---- */ \
    _Pragma("unroll") for (int j = 0; j < 2; ++j) { \
      aB[4+j*2+0] = *(const bf16x8*)(Bb_ + (wc*64 + 32 + j*16 + fr)*64 + c0s); \
      aB[4+j*2+1] = *(const bf16x8*)(Bb_ + (wc*64 + 32 + j*16 + fr)*64 + c1s); \
    } \
    if (st) { \
      gload16(srcA0 + ko2, Sn_ + tid8); \
      gload16(srcA2 + ko2, Sn_ + 8192 + tid8); \
    } \
    RAWBAR(); LGKM0(); \
    __builtin_amdgcn_s_setprio(1); \
    _Pragma("unroll") for (int i = 0; i < 4; ++i) \
      _Pragma("unroll") for (int j = 0; j < 2; ++j) { \
        acc[i][2+j] = __builtin_amdgcn_mfma_f32_16x16x32_bf16(aA[i*2+0], aB[4+j*2+0], acc[i][2+j], 0, 0, 0); \
        acc[i][2+j] = __builtin_amdgcn_mfma_f32_16x16x32_bf16(aA[i*2+1], aB[4+j*2+1], acc[i][2+j], 0, 0, 0); \
      } \
    __builtin_amdgcn_s_setprio(0); \
    RAWBAR(); \
    /* ---- ph2: read A-mh1 (8); stage B0..3(t+2); MFMA quad (1,0) ---- */ \
    _Pragma("unroll") for (int i = 0; i < 4; ++i) { \
      aA[i*2+0] = *(const bf16x8*)(Ab_ + (wr*128 + 64 + i*16 + fr)*64 + c0s); \
      aA[i*2+1] = *(const bf16x8*)(Ab_ + (wr*128 + 64 + i*16 + fr)*64 + c1s); \
    } \
    if (st) { \
      gload16(srcB0 + ko2, Sn_ + 16384 + tid8); \
      gload16(srcB1 + ko2, Sn_ + 20480 + tid8); \
      gload16(srcB2 + ko2, Sn_ + 24576 + tid8); \
      gload16(srcB3 + ko2, Sn_ + 28672 + tid8); \
    } \
    RAWBAR(); LGKM0(); \
    __builtin_amdgcn_s_setprio(1); \
    _Pragma("unroll") for (int i = 0; i < 4; ++i) \
      _Pragma("unroll") for (int j = 0; j < 2; ++j) { \
        acc[4+i][j] = __builtin_amdgcn_mfma_f32_16x16x32_bf16(aA[i*2+0], aB[j*2+0], acc[4+i][j], 0, 0, 0); \
        acc[4+i][j] = __builtin_amdgcn_mfma_f32_16x16x32_bf16(aA[i*2+1], aB[j*2+1], acc[4+i][j], 0, 0, 0); \
      } \
    __builtin_amdgcn_s_setprio(0); \
    RAWBAR(); \
    /* ---- ph3: stage A13(t+2); MFMA quad (1,1); gate ---- */ \
    if (st) { \
      gload16(srcA1 + ko2, Sn_ + 4096 + tid8); \
      gload16(srcA3 + ko2, Sn_ + 12288 + tid8); \
    } \
    __builtin_amdgcn_s_setprio(1); \
    _Pragma("unroll") for (int i = 0; i < 4; ++i) \
      _Pragma("unroll") for (int j = 0; j < 2; ++j) { \
        acc[4+i][2+j] = __builtin_amdgcn_mfma_f32_16x16x32_bf16(aA[i*2+0], aB[4+j*2+0], acc[4+i][2+j], 0, 0, 0); \
        acc[4+i][2+j] = __builtin_amdgcn_mfma_f32_16x16x32_bf16(aA[i*2+1], aB[4+j*2+1], acc[4+i][2+j], 0, 0, 0); \
      } \
    __builtin_amdgcn_s_setprio(0); \
    if (st) { VMCNT(8); } else { VMCNT(0); } \
    RAWBAR(); \
  } \
} while (0)

// ---------------- FFN up GEMM: h = gelu(A @ W1^T + b1) ----------------
__global__ __launch_bounds__(512, 2) void ffn1_gemm(const bf16* __restrict__ xb,
                                                    const bf16* __restrict__ w1t,
                                                    const float* __restrict__ bias1,
                                                    const int* __restrict__ sel,
                                                    bf16* __restrict__ hout,
                                                    int routed) {
  const int e = blockIdx.z;
  const bf16* Bw = w1t + (routed ? (size_t)e * HFFN * DMODEL : 0);
  const float* bias = bias1 + (routed ? (size_t)e * HFFN : 0);
  bf16* hb = hout + (routed ? (size_t)e * CAP * HFFN : 0);
  int bx, by;
  xcd_remap(bx, by);
  const int m0 = by * 256, n0 = bx * 256;
  __shared__ __align__(16) bf16 smem[65536];   // 128 KiB: 2 x (A 16K | B 16K bf16)
  const int tid = threadIdx.x, lane = tid & 63, wave = tid >> 6;
  const int wr = wave >> 2, wc = wave & 3;
  const int tid8 = tid * 8;

  // staging geometry: slab = 64 rows x 64 cols (8KB, one gload16 / 512 thr)
  const int srow = tid >> 3, sch = tid & 7;
  const int schs = sch ^ (srow & 7);
  const bf16 *srcA0, *srcA1, *srcA2, *srcA3, *srcB0, *srcB1, *srcB2, *srcB3;
  {
    int ra0 = routed ? sel[e * CAP + m0 + srow]       : (m0 + srow);
    int ra1 = routed ? sel[e * CAP + m0 + 64 + srow]  : (m0 + 64 + srow);
    int ra2 = routed ? sel[e * CAP + m0 + 128 + srow] : (m0 + 128 + srow);
    int ra3 = routed ? sel[e * CAP + m0 + 192 + srow] : (m0 + 192 + srow);
    srcA0 = xb + (size_t)ra0 * DMODEL + schs * 8;
    srcA1 = xb + (size_t)ra1 * DMODEL + schs * 8;
    srcA2 = xb + (size_t)ra2 * DMODEL + schs * 8;
    srcA3 = xb + (size_t)ra3 * DMODEL + schs * 8;
    srcB0 = Bw + (size_t)(n0 + srow) * DMODEL + schs * 8;
    srcB1 = Bw + (size_t)(n0 + 64 + srow) * DMODEL + schs * 8;
    srcB2 = Bw + (size_t)(n0 + 128 + srow) * DMODEL + schs * 8;
    srcB3 = Bw + (size_t)(n0 + 192 + srow) * DMODEL + schs * 8;
  }

  f32x4 acc[8][4];
  #pragma unroll
  for (int i = 0; i < 8; ++i)
    #pragma unroll
    for (int j = 0; j < 4; ++j) acc[i][j] = (f32x4){0.f, 0.f, 0.f, 0.f};

  const int fr = lane & 15;
  const int k8 = lane >> 4;
  const int sw = lane & 7;
  const int c0s = (k8 ^ sw) * 8;
  const int c1s = ((k8 + 4) ^ sw) * 8;

  KLOOP8(DMODEL / 64);

  // epilogue: bias+gelu -> bf16, two 128-row halves through swizzled LDS bounce
  #pragma unroll
  for (int half = 0; half < 2; ++half) {
    if (wr == half) {
      #pragma unroll
      for (int i = 0; i < 8; ++i) {
        #pragma unroll
        for (int j = 0; j < 4; ++j) {
          const int nl = wc * 64 + j * 16 + fr;
          const float bb = bias[n0 + nl];
          #pragma unroll
          for (int q = 0; q < 4; ++q) {
            const int ml = i * 16 + (lane >> 4) * 4 + q;   // 0..127 in half
            smem[ml * 256 + (nl ^ (((ml >> 2) & 7) << 4))] =
                (bf16)gelu_f(acc[i][j][q] + bb);
          }
        }
      }
    }
    __syncthreads();
    #pragma unroll
    for (int p = 0; p < 8; ++p) {
      const int flat = p * 512 + tid;
      const int row = flat >> 5, nc8 = flat & 31;
      uint4 v = *(const uint4*)(smem + row * 256 + ((nc8 * 8) ^ (((row >> 2) & 7) << 4)));
      *(uint4*)(hb + (size_t)(m0 + half * 128 + row) * HFFN + n0 + nc8 * 8) = v;
    }
    __syncthreads();
  }
}

// ---------------- FFN down GEMM: y = h @ W2^T + b2 ----------------
__global__ __launch_bounds__(512, 2) void ffn2_gemm(const bf16* __restrict__ hbuf,
                                                    const bf16* __restrict__ w2t,
                                                    const float* __restrict__ bias2,
                                                    const int* __restrict__ sel,
                                                    const float* __restrict__ scr,
                                                    float* __restrict__ out,
                                                    int routed) {
  const int e = blockIdx.z;
  const bf16* Ab = hbuf + (routed ? (size_t)e * CAP * HFFN : 0);
  const bf16* Bw = w2t + (routed ? (size_t)e * DMODEL * HFFN : 0);
  const float* bias = bias2 + (routed ? (size_t)e * DMODEL : 0);
  int bx, by;
  xcd_remap(bx, by);
  const int m0 = by * 256, n0 = bx * 256;
  __shared__ __align__(16) bf16 smem[65536];
  __shared__ int s_tok[256];
  __shared__ float s_scl[256];
  const int tid = threadIdx.x, lane = tid & 63, wave = tid >> 6;
  const int wr = wave >> 2, wc = wave & 3;
  const int tid8 = tid * 8;

  const int srow = tid >> 3, sch = tid & 7;
  const int schs = sch ^ (srow & 7);
  const bf16* srcA0 = Ab + (size_t)(m0 + srow) * HFFN + schs * 8;
  const bf16* srcA1 = Ab + (size_t)(m0 + 64 + srow) * HFFN + schs * 8;
  const bf16* srcA2 = Ab + (size_t)(m0 + 128 + srow) * HFFN + schs * 8;
  const bf16* srcA3 = Ab + (size_t)(m0 + 192 + srow) * HFFN + schs * 8;
  const bf16* srcB0 = Bw + (size_t)(n0 + srow) * HFFN + schs * 8;
  const bf16* srcB1 = Bw + (size_t)(n0 + 64 + srow) * HFFN + schs * 8;
  const bf16* srcB2 = Bw + (size_t)(n0 + 128 + srow) * HFFN + schs * 8;
  const bf16* srcB3 = Bw + (size_t)(n0 + 192 + srow) * HFFN + schs * 8;
  if (routed && tid < 256) {
    s_tok[tid] = sel[e * CAP + m0 + tid];
    s_scl[tid] = scr[e * CAP + m0 + tid];
  }

  f32x4 acc[8][4];
  #pragma unroll
  for (int i = 0; i < 8; ++i)
    #pragma unroll
    for (int j = 0; j < 4; ++j) acc[i][j] = (f32x4){0.f, 0.f, 0.f, 0.f};

  const int fr = lane & 15;
  const int k8 = lane >> 4;
  const int sw = lane & 7;
  const int c0s = (k8 ^ sw) * 8;
  const int c1s = ((k8 + 4) ^ sw) * 8;

  KLOOP8(HFFN / 64);

  if (!routed) {
    #pragma unroll
    for (int i = 0; i < 8; ++i) {
      #pragma unroll
      for (int j = 0; j < 4; ++j) {
        const int nl = wc * 64 + j * 16 + fr;
        const float bb = bias[n0 + nl];
        #pragma unroll
        for (int q = 0; q < 4; ++q) {
          const int ml = wr * 128 + i * 16 + (lane >> 4) * 4 + q;
          out[(size_t)(m0 + ml) * DMODEL + n0 + nl] = acc[i][j][q] + bb;
        }
      }
    }
  } else {
    __syncthreads();
    #pragma unroll
    for (int i = 0; i < 8; ++i) {
      #pragma unroll
      for (int j = 0; j < 4; ++j) {
        const int nl = wc * 64 + j * 16 + fr;
        const float bb = bias[n0 + nl];
        #pragma unroll
        for (int q = 0; q < 4; ++q) {
          const int ml = wr * 128 + i * 16 + (lane >> 4) * 4 + q;
          const int tok = s_tok[ml];
          const float sc = s_scl[ml];
          atomicAdd(out + (size_t)tok * DMODEL + n0 + nl, (acc[i][j][q] + bb) * sc);
        }
      }
    }
  }
}

extern "C" void kernel_launch(void* const* d_in, const int* in_sizes, int n_in,
                              void* d_out, int out_size, void* d_ws, size_t ws_size,
                              hipStream_t stream) {
  const float* x   = (const float*)d_in[0];
  const float* gw  = (const float*)d_in[1];
  const float* ew1 = (const float*)d_in[2];
  const float* eb1 = (const float*)d_in[3];
  const float* ew2 = (const float*)d_in[4];
  const float* eb2 = (const float*)d_in[5];
  const float* sw1 = (const float*)d_in[6];
  const float* sb1 = (const float*)d_in[7];
  const float* sw2 = (const float*)d_in[8];
  const float* sb2 = (const float*)d_in[9];
  float* out = (float*)d_out;

  char* ws = (char*)d_ws;
  size_t off = 0;
  bf16* xb      = (bf16*)(ws + off); off += (size_t)NTOK * DMODEL * 2;
  bf16* w1t     = (bf16*)(ws + off); off += (size_t)9 * HFFN * DMODEL * 2;
  bf16* w2t     = (bf16*)(ws + off); off += (size_t)9 * DMODEL * HFFN * 2;
  bf16* hbuf    = (bf16*)(ws + off); off += (size_t)NTOK * HFFN * 2;
  float* probs  = (float*)(ws + off); off += (size_t)NEXP * NTOK * 4;
  int* selidx   = (int*)(ws + off);   off += (size_t)NEXP * CAP * 4;
  float* selscr = (float*)(ws + off); off += (size_t)NEXP * CAP * 4;

  cvt_x_kernel<<<dim3(NTOK * DMODEL / 8 / 256), dim3(256), 0, stream>>>(x, xb);
  router_kernel<<<dim3(NTOK), dim3(64), 0, stream>>>(x, gw, probs);
  topk_kernel<<<dim3(NEXP), dim3(256), 0, stream>>>(probs, selidx, selscr);
  transpose_cvt<<<dim3(HFFN / 64, DMODEL / 64, 9), dim3(256), 0, stream>>>(ew1, sw1, w1t, DMODEL, HFFN);
  transpose_cvt<<<dim3(DMODEL / 64, HFFN / 64, 9), dim3(256), 0, stream>>>(ew2, sw2, w2t, HFFN, DMODEL);

  ffn1_gemm<<<dim3(HFFN / 256, NTOK / 256, 1), dim3(512), 0, stream>>>(
      xb, w1t + (size_t)8 * HFFN * DMODEL, sb1, (const int*)nullptr, hbuf, 0);
  ffn2_gemm<<<dim3(DMODEL / 256, NTOK / 256, 1), dim3(512), 0, stream>>>(
      hbuf, w2t + (size_t)8 * DMODEL * HFFN, sb2, (const int*)nullptr, (const float*)nullptr, out, 0);

  ffn1_gemm<<<dim3(HFFN / 256, CAP / 256, NEXP), dim3(512), 0, stream>>>(
      xb, w1t, eb1, selidx, hbuf, 1);
  ffn2_gemm<<<dim3(DMODEL / 256, CAP / 256, NEXP), dim3(512), 0, stream>>>(
      hbuf, w2t, eb2, selidx, selscr, out, 1);
}

// Round 7
// 821.307 us; speedup vs baseline: 1.4310x; 1.0924x over previous
//
#include <hip/hip_runtime.h>

typedef __bf16 bf16;
typedef __bf16 bf16x8 __attribute__((ext_vector_type(8)));
typedef float f32x4 __attribute__((ext_vector_type(4)));

#define NTOK 16384
#define DMODEL 1024
#define HFFN 4096
#define NEXP 8
#define CAP 2048

#define VMCNT(n) asm volatile("s_waitcnt vmcnt(" #n ")" ::: "memory")
#define LGKM0() do { asm volatile("s_waitcnt lgkmcnt(0)" ::: "memory"); \
                     __builtin_amdgcn_sched_barrier(0); } while (0)
#define BARRIER() __builtin_amdgcn_s_barrier()

__device__ __forceinline__ void gload16(const void* g, void* l) {
  __builtin_amdgcn_global_load_lds((const __attribute__((address_space(1))) void*)g,
                                   (__attribute__((address_space(3))) void*)l, 16, 0, 0);
}

// exact tanh-approx gelu via sigma identity: 0.5v(1+tanh(u)) = v*sigmoid(2u)
__device__ __forceinline__ float gelu_f(float v) {
  float t = v * v;
  float s2 = v * fmaf(0.10294358f, t, 2.3022084f);   // 2u*log2(e)
  float e = __builtin_exp2f(-s2);
  return v * __builtin_amdgcn_rcpf(1.0f + e);
}

// XCD-aware remap: all N-slots (bx) of one M-panel (by) land on one XCD.
__device__ __forceinline__ void xcd_remap(int& bx, int& by) {
  const int gx = gridDim.x;
  const int lg = 31 - __clz((unsigned)gx);
  const int w = blockIdx.x + gx * blockIdx.y;
  bx = (w >> 3) & (gx - 1);
  by = (w & 7) | (((w >> 3) >> lg) << 3);
}

// ---------------- x: f32 -> bf16 ----------------
__global__ __launch_bounds__(256) void cvt_x_kernel(const float* __restrict__ x,
                                                    bf16* __restrict__ xb) {
  int i = blockIdx.x * blockDim.x + threadIdx.x;
  const float4* a = (const float4*)x + (size_t)i * 2;
  float4 v0 = a[0], v1 = a[1];
  bf16x8 o;
  o[0]=(bf16)v0.x; o[1]=(bf16)v0.y; o[2]=(bf16)v0.z; o[3]=(bf16)v0.w;
  o[4]=(bf16)v1.x; o[5]=(bf16)v1.y; o[6]=(bf16)v1.z; o[7]=(bf16)v1.w;
  *(bf16x8*)(xb + (size_t)i * 8) = o;
}

// ---------------- router ----------------
__global__ __launch_bounds__(64) void router_kernel(const float* __restrict__ x,
                                                    const float* __restrict__ gw,
                                                    float* __restrict__ probs) {
  int t = blockIdx.x;
  int l = threadIdx.x;
  int e = l & 7, chunk = l >> 3;
  const float* xr = x + (size_t)t * DMODEL + chunk * 128;
  const float* gwr = gw + (size_t)(chunk * 128) * NEXP + e;
  float a0 = 0.f, a1 = 0.f;
  #pragma unroll
  for (int d = 0; d < 128; d += 8) {
    float4 xv = *(const float4*)(xr + d);
    float4 xw = *(const float4*)(xr + d + 4);
    a0 += xv.x * gwr[(d+0)*8] + xv.y * gwr[(d+1)*8] + xv.z * gwr[(d+2)*8] + xv.w * gwr[(d+3)*8];
    a1 += xw.x * gwr[(d+4)*8] + xw.y * gwr[(d+5)*8] + xw.z * gwr[(d+6)*8] + xw.w * gwr[(d+7)*8];
  }
  float acc = a0 + a1;
  acc += __shfl_xor(acc, 8);
  acc += __shfl_xor(acc, 16);
  acc += __shfl_xor(acc, 32);
  float m = acc;
  m = fmaxf(m, __shfl_xor(m, 1));
  m = fmaxf(m, __shfl_xor(m, 2));
  m = fmaxf(m, __shfl_xor(m, 4));
  float ex = expf(acc - m);
  float s = ex;
  s += __shfl_xor(s, 1); s += __shfl_xor(s, 2); s += __shfl_xor(s, 4);
  if (l < 8) probs[(size_t)e * NTOK + t] = ex / s;
}

// ---------------- per-expert top-2048 radix select ----------------
__global__ __launch_bounds__(256) void topk_kernel(const float* __restrict__ probs,
                                                   int* __restrict__ oidx,
                                                   float* __restrict__ oscr) {
  const int e = blockIdx.x;
  const float* p = probs + (size_t)e * NTOK;
  const int t = threadIdx.x;
  __shared__ unsigned hist[256];
  __shared__ unsigned sg[256], sq[256];
  __shared__ unsigned bcast[4];
  unsigned pref = 0, krem = CAP;
  for (int pass = 0; pass < 4; ++pass) {
    const int sh = 24 - pass * 8;
    hist[t] = 0;
    __syncthreads();
    for (int j = 0; j < 64; ++j) {
      unsigned u = __float_as_uint(p[t * 64 + j]);
      bool ok = (pass == 0) || ((u >> (sh + 8)) == pref);
      if (ok) atomicAdd(&hist[(u >> sh) & 255u], 1u);
    }
    __syncthreads();
    if (t == 0) {
      unsigned cum = 0; int b = 255;
      for (; b > 0; --b) {
        unsigned c = hist[b];
        if (cum + c >= krem) break;
        cum += c;
      }
      bcast[0] = (pref << 8) | (unsigned)b;
      bcast[1] = krem - cum;
    }
    __syncthreads();
    pref = bcast[0];
    krem = bcast[1];
  }
  const unsigned thr = pref;
  const unsigned neq_take = krem;
  unsigned cgt = 0, ceq = 0;
  for (int j = 0; j < 64; ++j) {
    unsigned u = __float_as_uint(p[t * 64 + j]);
    cgt += (u > thr);
    ceq += (u == thr);
  }
  sg[t] = cgt; sq[t] = ceq;
  __syncthreads();
  if (t == 0) {
    unsigned ag = 0, aq = 0;
    for (int i = 0; i < 256; ++i) {
      unsigned g = sg[i], q = sq[i];
      sg[i] = ag; sq[i] = aq;
      ag += g; aq += q;
    }
    bcast[2] = ag;
  }
  __syncthreads();
  const unsigned ngt = bcast[2];
  unsigned og = sg[t], oq = sq[t];
  int* oi = oidx + e * CAP;
  float* os = oscr + e * CAP;
  for (int j = 0; j < 64; ++j) {
    int tok = t * 64 + j;
    float pv = p[tok];
    unsigned u = __float_as_uint(pv);
    if (u > thr) {
      oi[og] = tok; os[og] = pv; ++og;
    } else if (u == thr) {
      if (oq < neq_take) { oi[ngt + oq] = tok; os[ngt + oq] = pv; }
      ++oq;
    }
  }
}

// ---------------- weight transpose + cvt ----------------
__global__ __launch_bounds__(256) void transpose_cvt(const float* __restrict__ in_e,
                                                     const float* __restrict__ in_s,
                                                     bf16* __restrict__ outp,
                                                     int R, int C) {
  int z = blockIdx.z;
  const float* in = (z < 8) ? (in_e + (size_t)z * (size_t)R * C) : in_s;
  bf16* out = outp + (size_t)z * (size_t)R * C;
  __shared__ float tile[64][65];
  int tx = threadIdx.x & 63, ty = threadIdx.x >> 6;
  int c0 = blockIdx.x * 64, r0 = blockIdx.y * 64;
  #pragma unroll
  for (int j = 0; j < 16; ++j) {
    int r = ty + j * 4;
    tile[r][tx] = in[(size_t)(r0 + r) * C + c0 + tx];
  }
  __syncthreads();
  #pragma unroll
  for (int j = 0; j < 16; ++j) {
    int c = ty + j * 4;
    out[(size_t)(c0 + c) * R + r0 + tx] = (bf16)tile[tx][c];
  }
}

// =====================================================================
// 256x256 tile, BK=64, 512 thr, 2 LDS buffers, 4 phases/K-tile, ONE
// barrier per phase. Stage schedule (proof rests on per-wave LGKM0 +
// barrier transitivity, no timing windows):
//   ph0: read A-lo(8)+B-lo(4); stage A1,A3(t+1) -> OTHER buf; BAR; LGKM0; MFMA(0,0)
//   ph1: read B-hi(4);                                        BAR; LGKM0; MFMA(0,1)
//   ph2: read A-hi(8, reuse aA); stage A0,A2(t+2) -> cur buf; BAR; LGKM0; MFMA(1,0)
//        [A0,A2 reads done at ph0-LGKM0; ph1's BAR orders them before this stage]
//   ph3: stage B0-3(t+2) -> cur buf; gate vmcnt(6); BAR; MFMA(1,1)
//        [B reads done by ph1-LGKM0; ph2's BAR orders; gate drains A13(t+1)]
// No barrier after MFMA(1,1): next ph0 reads the OTHER buffer (disjoint
// from all in-flight stages) -> cross-wave LDS/MFMA pipe overlap.
// =====================================================================

#define STAGE_TILE_ALL(tt) do { \
  bf16* D_ = smem + (((tt) & 1) << 15); \
  const int ko_ = (tt) * 64; \
  gload16(srcA0 + ko_, D_ + tid8); \
  gload16(srcA1 + ko_, D_ + 4096 + tid8); \
  gload16(srcA2 + ko_, D_ + 8192 + tid8); \
  gload16(srcA3 + ko_, D_ + 12288 + tid8); \
  gload16(srcB0 + ko_, D_ + 16384 + tid8); \
  gload16(srcB1 + ko_, D_ + 20480 + tid8); \
  gload16(srcB2 + ko_, D_ + 24576 + tid8); \
  gload16(srcB3 + ko_, D_ + 28672 + tid8); \
} while (0)

#define KLOOP8(NT) do { \
  STAGE_TILE_ALL(0); \
  { /* tile1 partial: A0,A2 + B0-3 (A1,A3 staged at ph0 of t=0) */ \
    bf16* D_ = smem + 32768; \
    gload16(srcA0 + 64, D_ + tid8); \
    gload16(srcA2 + 64, D_ + 8192 + tid8); \
    gload16(srcB0 + 64, D_ + 16384 + tid8); \
    gload16(srcB1 + 64, D_ + 20480 + tid8); \
    gload16(srcB2 + 64, D_ + 24576 + tid8); \
    gload16(srcB3 + 64, D_ + 28672 + tid8); \
  } \
  VMCNT(6); \
  BARRIER(); \
  for (int t = 0; t < (NT); ++t) { \
    const bf16* Ab_ = smem + ((t & 1) << 15); \
    const bf16* Bb_ = Ab_ + 16384; \
    bf16* Scur = smem + ((t & 1) << 15); \
    bf16* Snxt = smem + (((t + 1) & 1) << 15); \
    const int ko1 = (t + 1) * 64, ko2 = (t + 2) * 64; \
    const bool st1 = (t + 1) < (NT), st2 = (t + 2) < (NT); \
    bf16x8 aA[8], aB[8]; \
    /* ---- ph0 ---- */ \
    _Pragma("unroll") for (int i = 0; i < 4; ++i) { \
      aA[i*2+0] = *(const bf16x8*)(Ab_ + (wr*128 + i*16 + fr)*64 + c0s); \
      aA[i*2+1] = *(const bf16x8*)(Ab_ + (wr*128 + i*16 + fr)*64 + c1s); \
    } \
    _Pragma("unroll") for (int j = 0; j < 2; ++j) { \
      aB[j*2+0] = *(const bf16x8*)(Bb_ + (wc*64 + j*16 + fr)*64 + c0s); \
      aB[j*2+1] = *(const bf16x8*)(Bb_ + (wc*64 + j*16 + fr)*64 + c1s); \
    } \
    if (st1) { \
      gload16(srcA1 + ko1, Snxt + 4096 + tid8); \
      gload16(srcA3 + ko1, Snxt + 12288 + tid8); \
    } \
    BARRIER(); LGKM0(); \
    __builtin_amdgcn_s_setprio(1); \
    _Pragma("unroll") for (int i = 0; i < 4; ++i) \
      _Pragma("unroll") for (int j = 0; j < 2; ++j) { \
        acc[i][j] = __builtin_amdgcn_mfma_f32_16x16x32_bf16(aA[i*2+0], aB[j*2+0], acc[i][j], 0, 0, 0); \
        acc[i][j] = __builtin_amdgcn_mfma_f32_16x16x32_bf16(aA[i*2+1], aB[j*2+1], acc[i][j], 0, 0, 0); \
      } \
    __builtin_amdgcn_s_setprio(0); \
    /* ---- ph1 ---- */ \
    _Pragma("unroll") for (int j = 0; j < 2; ++j) { \
      aB[4+j*2+0] = *(const bf16x8*)(Bb_ + (wc*64 + 32 + j*16 + fr)*64 + c0s); \
      aB[4+j*2+1] = *(const bf16x8*)(Bb_ + (wc*64 + 32 + j*16 + fr)*64 + c1s); \
    } \
    BARRIER(); LGKM0(); \
    __builtin_amdgcn_s_setprio(1); \
    _Pragma("unroll") for (int i = 0; i < 4; ++i) \
      _Pragma("unroll") for (int j = 0; j < 2; ++j) { \
        acc[i][2+j] = __builtin_amdgcn_mfma_f32_16x16x32_bf16(aA[i*2+0], aB[4+j*2+0], acc[i][2+j], 0, 0, 0); \
        acc[i][2+j] = __builtin_amdgcn_mfma_f32_16x16x32_bf16(aA[i*2+1], aB[4+j*2+1], acc[i][2+j], 0, 0, 0); \
      } \
    __builtin_amdgcn_s_setprio(0); \
    /* ---- ph2 ---- */ \
    _Pragma("unroll") for (int i = 0; i < 4; ++i) { \
      aA[i*2+0] = *(const bf16x8*)(Ab_ + (wr*128 + 64 + i*16 + fr)*64 + c0s); \
      aA[i*2+1] = *(const bf16x8*)(Ab_ + (wr*128 + 64 + i*16 + fr)*64 + c1s); \
    } \
    if (st2) { \
      gload16(srcA0 + ko2, Scur + tid8); \
      gload16(srcA2 + ko2, Scur + 8192 + tid8); \
    } \
    BARRIER(); LGKM0(); \
    __builtin_amdgcn_s_setprio(1); \
    _Pragma("unroll") for (int i = 0; i < 4; ++i) \
      _Pragma("unroll") for (int j = 0; j < 2; ++j) { \
        acc[4+i][j] = __builtin_amdgcn_mfma_f32_16x16x32_bf16(aA[i*2+0], aB[j*2+0], acc[4+i][j], 0, 0, 0); \
        acc[4+i][j] = __builtin_amdgcn_mfma_f32_16x16x32_bf16(aA[i*2+1], aB[j*2+1], acc[4+i][j], 0, 0, 0); \
      } \
    __builtin_amdgcn_s_setprio(0); \
    /* ---- ph3 ---- */ \
    if (st2) { \
      gload16(srcB0 + ko2, Scur + 16384 + tid8); \
      gload16(srcB1 + ko2, Scur + 20480 + tid8); \
      gload16(srcB2 + ko2, Scur + 24576 + tid8); \
      gload16(srcB3 + ko2, Scur + 28672 + tid8); \
    } \
    if (st2) { VMCNT(6); } else { VMCNT(0); } \
    BARRIER(); \
    __builtin_amdgcn_s_setprio(1); \
    _Pragma("unroll") for (int i = 0; i < 4; ++i) \
      _Pragma("unroll") for (int j = 0; j < 2; ++j) { \
        acc[4+i][2+j] = __builtin_amdgcn_mfma_f32_16x16x32_bf16(aA[i*2+0], aB[4+j*2+0], acc[4+i][2+j], 0, 0, 0); \
        acc[4+i][2+j] = __builtin_amdgcn_mfma_f32_16x16x32_bf16(aA[i*2+1], aB[4+j*2+1], acc[4+i][2+j], 0, 0, 0); \
      } \
    __builtin_amdgcn_s_setprio(0); \
  } \
} while (0)

// ---------------- FFN up GEMM: h = gelu(A @ W1^T + b1) ----------------
__global__ __launch_bounds__(512, 2) void ffn1_gemm(const bf16* __restrict__ xb,
                                                    const bf16* __restrict__ w1t,
                                                    const float* __restrict__ bias1,
                                                    const int* __restrict__ sel,
                                                    bf16* __restrict__ hout,
                                                    int routed) {
  const int e = blockIdx.z;
  const bf16* Bw = w1t + (routed ? (size_t)e * HFFN * DMODEL : 0);
  const float* bias = bias1 + (routed ? (size_t)e * HFFN : 0);
  bf16* hb = hout + (routed ? (size_t)e * CAP * HFFN : 0);
  int bx, by;
  xcd_remap(bx, by);
  const int m0 = by * 256, n0 = bx * 256;
  __shared__ __align__(16) bf16 smem[65536];   // 128 KiB: 2 x (A 16K | B 16K bf16)
  const int tid = threadIdx.x, lane = tid & 63, wave = tid >> 6;
  const int wr = wave >> 2, wc = wave & 3;
  const int tid8 = tid * 8;

  const int srow = tid >> 3, sch = tid & 7;
  const int schs = sch ^ (srow & 7);
  const bf16 *srcA0, *srcA1, *srcA2, *srcA3, *srcB0, *srcB1, *srcB2, *srcB3;
  {
    int ra0 = routed ? sel[e * CAP + m0 + srow]       : (m0 + srow);
    int ra1 = routed ? sel[e * CAP + m0 + 64 + srow]  : (m0 + 64 + srow);
    int ra2 = routed ? sel[e * CAP + m0 + 128 + srow] : (m0 + 128 + srow);
    int ra3 = routed ? sel[e * CAP + m0 + 192 + srow] : (m0 + 192 + srow);
    srcA0 = xb + (size_t)ra0 * DMODEL + schs * 8;
    srcA1 = xb + (size_t)ra1 * DMODEL + schs * 8;
    srcA2 = xb + (size_t)ra2 * DMODEL + schs * 8;
    srcA3 = xb + (size_t)ra3 * DMODEL + schs * 8;
    srcB0 = Bw + (size_t)(n0 + srow) * DMODEL + schs * 8;
    srcB1 = Bw + (size_t)(n0 + 64 + srow) * DMODEL + schs * 8;
    srcB2 = Bw + (size_t)(n0 + 128 + srow) * DMODEL + schs * 8;
    srcB3 = Bw + (size_t)(n0 + 192 + srow) * DMODEL + schs * 8;
  }

  f32x4 acc[8][4];
  #pragma unroll
  for (int i = 0; i < 8; ++i)
    #pragma unroll
    for (int j = 0; j < 4; ++j) acc[i][j] = (f32x4){0.f, 0.f, 0.f, 0.f};

  const int fr = lane & 15;
  const int k8 = lane >> 4;
  const int sw = lane & 7;
  const int c0s = (k8 ^ sw) * 8;
  const int c1s = ((k8 + 4) ^ sw) * 8;

  KLOOP8(DMODEL / 64);

  // epilogue: bias+gelu -> bf16, two 128-row halves through swizzled LDS bounce
  __syncthreads();
  #pragma unroll
  for (int half = 0; half < 2; ++half) {
    if (wr == half) {
      #pragma unroll
      for (int i = 0; i < 8; ++i) {
        #pragma unroll
        for (int j = 0; j < 4; ++j) {
          const int nl = wc * 64 + j * 16 + fr;
          const float bb = bias[n0 + nl];
          #pragma unroll
          for (int q = 0; q < 4; ++q) {
            const int ml = i * 16 + (lane >> 4) * 4 + q;   // 0..127 in half
            smem[ml * 256 + (nl ^ (((ml >> 2) & 7) << 4))] =
                (bf16)gelu_f(acc[i][j][q] + bb);
          }
        }
      }
    }
    __syncthreads();
    #pragma unroll
    for (int p = 0; p < 8; ++p) {
      const int flat = p * 512 + tid;
      const int row = flat >> 5, nc8 = flat & 31;
      uint4 v = *(const uint4*)(smem + row * 256 + ((nc8 * 8) ^ (((row >> 2) & 7) << 4)));
      *(uint4*)(hb + (size_t)(m0 + half * 128 + row) * HFFN + n0 + nc8 * 8) = v;
    }
    __syncthreads();
  }
}

// ---------------- FFN down GEMM: y = h @ W2^T + b2 ----------------
__global__ __launch_bounds__(512, 2) void ffn2_gemm(const bf16* __restrict__ hbuf,
                                                    const bf16* __restrict__ w2t,
                                                    const float* __restrict__ bias2,
                                                    const int* __restrict__ sel,
                                                    const float* __restrict__ scr,
                                                    float* __restrict__ out,
                                                    int routed) {
  const int e = blockIdx.z;
  const bf16* Ab = hbuf + (routed ? (size_t)e * CAP * HFFN : 0);
  const bf16* Bw = w2t + (routed ? (size_t)e * DMODEL * HFFN : 0);
  const float* bias = bias2 + (routed ? (size_t)e * DMODEL : 0);
  int bx, by;
  xcd_remap(bx, by);
  const int m0 = by * 256, n0 = bx * 256;
  __shared__ __align__(16) bf16 smem[65536];
  __shared__ int s_tok[256];
  __shared__ float s_scl[256];
  const int tid = threadIdx.x, lane = tid & 63, wave = tid >> 6;
  const int wr = wave >> 2, wc = wave & 3;
  const int tid8 = tid * 8;

  const int srow = tid >> 3, sch = tid & 7;
  const int schs = sch ^ (srow & 7);
  const bf16* srcA0 = Ab + (size_t)(m0 + srow) * HFFN + schs * 8;
  const bf16* srcA1 = Ab + (size_t)(m0 + 64 + srow) * HFFN + schs * 8;
  const bf16* srcA2 = Ab + (size_t)(m0 + 128 + srow) * HFFN + schs * 8;
  const bf16* srcA3 = Ab + (size_t)(m0 + 192 + srow) * HFFN + schs * 8;
  const bf16* srcB0 = Bw + (size_t)(n0 + srow) * HFFN + schs * 8;
  const bf16* srcB1 = Bw + (size_t)(n0 + 64 + srow) * HFFN + schs * 8;
  const bf16* srcB2 = Bw + (size_t)(n0 + 128 + srow) * HFFN + schs * 8;
  const bf16* srcB3 = Bw + (size_t)(n0 + 192 + srow) * HFFN + schs * 8;
  if (routed && tid < 256) {
    s_tok[tid] = sel[e * CAP + m0 + tid];
    s_scl[tid] = scr[e * CAP + m0 + tid];
  }

  f32x4 acc[8][4];
  #pragma unroll
  for (int i = 0; i < 8; ++i)
    #pragma unroll
    for (int j = 0; j < 4; ++j) acc[i][j] = (f32x4){0.f, 0.f, 0.f, 0.f};

  const int fr = lane & 15;
  const int k8 = lane >> 4;
  const int sw = lane & 7;
  const int c0s = (k8 ^ sw) * 8;
  const int c1s = ((k8 + 4) ^ sw) * 8;

  KLOOP8(HFFN / 64);

  if (!routed) {
    #pragma unroll
    for (int i = 0; i < 8; ++i) {
      #pragma unroll
      for (int j = 0; j < 4; ++j) {
        const int nl = wc * 64 + j * 16 + fr;
        const float bb = bias[n0 + nl];
        #pragma unroll
        for (int q = 0; q < 4; ++q) {
          const int ml = wr * 128 + i * 16 + (lane >> 4) * 4 + q;
          out[(size_t)(m0 + ml) * DMODEL + n0 + nl] = acc[i][j][q] + bb;
        }
      }
    }
  } else {
    __syncthreads();
    #pragma unroll
    for (int i = 0; i < 8; ++i) {
      #pragma unroll
      for (int j = 0; j < 4; ++j) {
        const int nl = wc * 64 + j * 16 + fr;
        const float bb = bias[n0 + nl];
        #pragma unroll
        for (int q = 0; q < 4; ++q) {
          const int ml = wr * 128 + i * 16 + (lane >> 4) * 4 + q;
          const int tok = s_tok[ml];
          const float sc = s_scl[ml];
          atomicAdd(out + (size_t)tok * DMODEL + n0 + nl, (acc[i][j][q] + bb) * sc);
        }
      }
    }
  }
}

extern "C" void kernel_launch(void* const* d_in, const int* in_sizes, int n_in,
                              void* d_out, int out_size, void* d_ws, size_t ws_size,
                              hipStream_t stream) {
  const float* x   = (const float*)d_in[0];
  const float* gw  = (const float*)d_in[1];
  const float* ew1 = (const float*)d_in[2];
  const float* eb1 = (const float*)d_in[3];
  const float* ew2 = (const float*)d_in[4];
  const float* eb2 = (const float*)d_in[5];
  const float* sw1 = (const float*)d_in[6];
  const float* sb1 = (const float*)d_in[7];
  const float* sw2 = (const float*)d_in[8];
  const float* sb2 = (const float*)d_in[9];
  float* out = (float*)d_out;

  char* ws = (char*)d_ws;
  size_t off = 0;
  bf16* xb      = (bf16*)(ws + off); off += (size_t)NTOK * DMODEL * 2;
  bf16* w1t     = (bf16*)(ws + off); off += (size_t)9 * HFFN * DMODEL * 2;
  bf16* w2t     = (bf16*)(ws + off); off += (size_t)9 * DMODEL * HFFN * 2;
  bf16* hbuf    = (bf16*)(ws + off); off += (size_t)NTOK * HFFN * 2;
  float* probs  = (float*)(ws + off); off += (size_t)NEXP * NTOK * 4;
  int* selidx   = (int*)(ws + off);   off += (size_t)NEXP * CAP * 4;
  float* selscr = (float*)(ws + off); off += (size_t)NEXP * CAP * 4;

  cvt_x_kernel<<<dim3(NTOK * DMODEL / 8 / 256), dim3(256), 0, stream>>>(x, xb);
  router_kernel<<<dim3(NTOK), dim3(64), 0, stream>>>(x, gw, probs);
  topk_kernel<<<dim3(NEXP), dim3(256), 0, stream>>>(probs, selidx, selscr);
  transpose_cvt<<<dim3(HFFN / 64, DMODEL / 64, 9), dim3(256), 0, stream>>>(ew1, sw1, w1t, DMODEL, HFFN);
  transpose_cvt<<<dim3(DMODEL / 64, HFFN / 64, 9), dim3(256), 0, stream>>>(ew2, sw2, w2t, HFFN, DMODEL);

  ffn1_gemm<<<dim3(HFFN / 256, NTOK / 256, 1), dim3(512), 0, stream>>>(
      xb, w1t + (size_t)8 * HFFN * DMODEL, sb1, (const int*)nullptr, hbuf, 0);
  ffn2_gemm<<<dim3(DMODEL / 256, NTOK / 256, 1), dim3(512), 0, stream>>>(
      hbuf, w2t + (size_t)8 * DMODEL * HFFN, sb2, (const int*)nullptr, (const float*)nullptr, out, 0);

  ffn1_gemm<<<dim3(HFFN / 256, CAP / 256, NEXP), dim3(512), 0, stream>>>(
      xb, w1t, eb1, selidx, hbuf, 1);
  ffn2_gemm<<<dim3(DMODEL / 256, CAP / 256, NEXP), dim3(512), 0, stream>>>(
      hbuf, w2t, eb2, selidx, selscr, out, 1);
}